// Round 3
// baseline (913.889 us; speedup 1.0000x reference)
//
#include <hip/hip_runtime.h>
#include <stdint.h>

// MambaEncoder on MI355X (gfx950).
// ALL inputs and the output are FLOAT32 (per the reference). Intermediates are
// bf16 in workspace; GEMMs run bf16 MFMA with fp32 accumulation (2% threshold).
// Shapes: B=4, L=2048, d_model=512, hidden=256, d_inner=512, N=16, dt_rank=16, 2 dirs.

typedef unsigned short u16;
typedef __bf16 bf16x8 __attribute__((ext_vector_type(8)));
typedef float f32x4 __attribute__((ext_vector_type(4)));

__device__ __forceinline__ float b2f(u16 h) {
    union { unsigned int u; float f; } c; c.u = ((unsigned int)h) << 16; return c.f;
}
__device__ __forceinline__ u16 f2b(float f) {   // round-to-nearest-even
    union { float f; unsigned int u; } c; c.f = f;
    unsigned int r = c.u + 0x7FFFu + ((c.u >> 16) & 1u);
    return (u16)(r >> 16);
}

// ---------------------------------------------------------------------------
// bf16-MFMA GEMM: C[M,N] = act(A[M,K] @ W[N,K]^T + bias)
// W, bias: fp32 global inputs (converted to bf16 at staging).
// A: fp32 (AF32=1, global input) or bf16 u16 (AF32=0, intermediate).
// C: bf16 u16 intermediate, stride ldc, col-guard n<N.
// BM=BN=64, BK=32, block=256 (4 waves). flip: A row (b,l)->(b,2047-l), L=2048.
// ACT: 0=none, 1=softplus.
// ---------------------------------------------------------------------------
template<int ACT, int AF32>
__global__ __launch_bounds__(256)
void gemm_bf16(const void* __restrict__ Av, const float* __restrict__ W,
               const float* __restrict__ bias, u16* __restrict__ C,
               int M, int N, int K, int lda, int ldw, int ldc, int flip)
{
    // pad 40 (=32+8) bf16 per row: row stride 80B (16B-aligned), 2-way bank alias (free)
    __shared__ u16 As[64 * 40];
    __shared__ u16 Ws[64 * 40];
    const int tid  = threadIdx.x;
    const int n0   = blockIdx.x * 64;
    const int m0   = blockIdx.y * 64;
    const int r    = tid >> 2;      // staging row 0..63
    const int seg  = tid & 3;       // 8-elem segment 0..3
    const int w    = tid >> 6;      // wave 0..3
    const int lane = tid & 63;
    const int r16  = lane & 15;
    const int q    = lane >> 4;     // quad 0..3

    f32x4 acc[4];
    #pragma unroll
    for (int i = 0; i < 4; ++i) acc[i] = (f32x4){0.f, 0.f, 0.f, 0.f};

    const int KT = (K + 31) >> 5;
    for (int kt = 0; kt < KT; ++kt) {
        const int kk = (kt << 5) + seg * 8;
        // --- stage A row (M divisible by 64: row always valid) ---
        {
            int m   = m0 + r;
            int src = flip ? ((m & ~2047) | (2047 - (m & 2047))) : m;
            union { u16 s[8]; uint4 v; } t;
            if (AF32) {
                const float* sp = (const float*)Av + (size_t)src * lda;
                if (kk + 8 <= K) {
                    float4 f0 = *(const float4*)(sp + kk);
                    float4 f1 = *(const float4*)(sp + kk + 4);
                    t.s[0] = f2b(f0.x); t.s[1] = f2b(f0.y);
                    t.s[2] = f2b(f0.z); t.s[3] = f2b(f0.w);
                    t.s[4] = f2b(f1.x); t.s[5] = f2b(f1.y);
                    t.s[6] = f2b(f1.z); t.s[7] = f2b(f1.w);
                } else {
                    #pragma unroll
                    for (int e = 0; e < 8; ++e)
                        t.s[e] = ((kk + e) < K) ? f2b(sp[kk + e]) : (u16)0;
                }
            } else {
                const u16* sp = (const u16*)Av + (size_t)src * lda;
                if (kk + 8 <= K) {
                    t.v = *(const uint4*)(sp + kk);
                } else {
                    #pragma unroll
                    for (int e = 0; e < 8; ++e)
                        t.s[e] = ((kk + e) < K) ? sp[kk + e] : (u16)0;
                }
            }
            *(uint4*)(&As[r * 40 + seg * 8]) = t.v;
        }
        // --- stage W row n (fp32 -> bf16) ---
        {
            int n = n0 + r;
            const float* sp = W + (size_t)n * ldw;
            union { u16 s[8]; uint4 v; } t;
            if (n < N && kk + 8 <= K) {
                float4 f0 = *(const float4*)(sp + kk);
                float4 f1 = *(const float4*)(sp + kk + 4);
                t.s[0] = f2b(f0.x); t.s[1] = f2b(f0.y);
                t.s[2] = f2b(f0.z); t.s[3] = f2b(f0.w);
                t.s[4] = f2b(f1.x); t.s[5] = f2b(f1.y);
                t.s[6] = f2b(f1.z); t.s[7] = f2b(f1.w);
            } else {
                #pragma unroll
                for (int e = 0; e < 8; ++e)
                    t.s[e] = (n < N && (kk + e) < K) ? f2b(sp[kk + e]) : (u16)0;
            }
            *(uint4*)(&Ws[r * 40 + seg * 8]) = t.v;
        }
        __syncthreads();
        // A-frag: A[m=lane&15][k=quad*8+j]; B-frag: B[k=quad*8+j][n=lane&15] = W[n][k]
        bf16x8 af = *(const bf16x8*)(&As[(w * 16 + r16) * 40 + q * 8]);
        #pragma unroll
        for (int nt = 0; nt < 4; ++nt) {
            bf16x8 wf = *(const bf16x8*)(&Ws[(nt * 16 + r16) * 40 + q * 8]);
            acc[nt] = __builtin_amdgcn_mfma_f32_16x16x32_bf16(af, wf, acc[nt], 0, 0, 0);
        }
        __syncthreads();
    }
    // epilogue: D[row][col], col = lane&15, row = quad*4 + reg
    #pragma unroll
    for (int nt = 0; nt < 4; ++nt) {
        int n = n0 + nt * 16 + r16;
        if (n >= N) continue;
        float bv = bias ? bias[n] : 0.f;
        #pragma unroll
        for (int rg = 0; rg < 4; ++rg) {
            int m = m0 + w * 16 + q * 4 + rg;
            float v = acc[nt][rg] + bv;
            if (ACT == 1) v = (v > 20.f) ? v : __logf(1.f + __expf(v));
            C[(size_t)m * ldc + n] = f2b(v);
        }
    }
}

// ---------------------------------------------------------------------------
// Depthwise causal conv (4 taps) + silu. xz layout [2][4][2048][1024] bf16;
// xi = cols 0:512. cw/cb fp32 inputs. u [2][4][2048][512] bf16.
// Thread handles 8 channels at one (d,b,l).
// ---------------------------------------------------------------------------
__global__ __launch_bounds__(256)
void conv_silu_kernel(const u16* __restrict__ xz, const float* __restrict__ cw,
                      const float* __restrict__ cb, u16* __restrict__ ubuf)
{
    int g  = blockIdx.x * 256 + threadIdx.x;   // [bd:3][l:11][cg:6]
    int cg = g & 63;
    int l  = (g >> 6) & 2047;
    int bd = g >> 17;                           // d*4+b
    int d  = bd >> 2;
    int c0 = cg << 3;
    size_t rowb = (size_t)bd * 2048;

    float acc[8];
    #pragma unroll
    for (int i = 0; i < 8; ++i) acc[i] = cb[d * 512 + c0 + i];

    // weights: 8ch x 4tap contiguous fp32
    const float* wp = cw + (size_t)(d * 512 + c0) * 4;
    #pragma unroll
    for (int j = 0; j < 4; ++j) {
        int lj = l - 3 + j;
        if (lj >= 0) {
            uint4 xv = *(const uint4*)(xz + (rowb + lj) * 1024 + c0);
            const u16* xs = (const u16*)&xv;
            #pragma unroll
            for (int i = 0; i < 8; ++i)
                acc[i] = fmaf(b2f(xs[i]), wp[i * 4 + j], acc[i]);
        }
    }
    union { u16 s[8]; uint4 v; } o;
    #pragma unroll
    for (int i = 0; i < 8; ++i) {
        float x = acc[i];
        o.s[i] = f2b(x / (1.f + __expf(-x)));
    }
    *(uint4*)(ubuf + (rowb + l) * 512 + c0) = o.v;
}

// ---------------------------------------------------------------------------
// Sequential selective scan + fused gating and mean-pool accumulation.
// One thread per (d, b, ch, n): 65536 threads. 16-lane shfl reduce for y.
// Accumulates gsum[d*4+b][ch] = sum_t (y_t + u_t*Dv) * silu(z_t)  (fp32).
// dt lives in xz cols 0:512 (overwrote xi), z in cols 512:1024. A_log/Dp fp32.
// Distance-1 prefetch to cover load latency (1 wave/SIMD occupancy).
// ---------------------------------------------------------------------------
__global__ __launch_bounds__(256)
void scan_kernel(const u16* __restrict__ xz, const u16* __restrict__ ubuf,
                 const u16* __restrict__ dbc, const float* __restrict__ A_log,
                 const float* __restrict__ Dp, float* __restrict__ gsum)
{
    int g  = blockIdx.x * 256 + threadIdx.x;   // [bd:3][ch:9][n:4]
    int n  = g & 15;
    int ch = (g >> 4) & 511;
    int bd = g >> 13;
    int d  = bd >> 2;

    float a  = -__expf(A_log[(d * 512 + ch) * 16 + n]);
    float Dv = Dp[d * 512 + ch];
    size_t rowb = (size_t)bd * 2048;

    const u16* p_dt = xz  + rowb * 1024 + ch;
    const u16* p_z  = xz  + rowb * 1024 + 512 + ch;
    const u16* p_u  = ubuf + rowb * 512 + ch;
    const u16* p_B  = dbc + rowb * 48 + 16 + n;
    const u16* p_C  = dbc + rowb * 48 + 32 + n;

    float n_dt = b2f(*p_dt), n_u = b2f(*p_u), n_z = b2f(*p_z);
    float n_B = b2f(*p_B), n_C = b2f(*p_C);

    float h = 0.f, gacc = 0.f;
    for (int t = 0; t < 2048; ++t) {
        float dt = n_dt, uv = n_u, zv = n_z, Bv = n_B, Cv = n_C;
        if (t < 2047) {   // prefetch t+1 (uniform branch)
            p_dt += 1024; p_z += 1024; p_u += 512; p_B += 48; p_C += 48;
            n_dt = b2f(*p_dt); n_u = b2f(*p_u); n_z = b2f(*p_z);
            n_B = b2f(*p_B); n_C = b2f(*p_C);
        }
        float dA = __expf(dt * a);
        h = fmaf(dA, h, dt * uv * Bv);
        float p = h * Cv;
        p += __shfl_xor(p, 1);
        p += __shfl_xor(p, 2);
        p += __shfl_xor(p, 4);
        p += __shfl_xor(p, 8);
        float sz = zv / (1.f + __expf(-zv));
        gacc = fmaf(p + uv * Dv, sz, gacc);
    }
    if (n == 0) gsum[bd * 512 + ch] = gacc;
}

// ---------------------------------------------------------------------------
// Epilogue: gbar = gsum/L; embd[512] = concat_d(gbar[d] @ out_w[d]^T);
// out[b,i] = embd @ op_w[i,:]^T + op_b[i]  (all fp32). One block per batch b.
// ---------------------------------------------------------------------------
__global__ __launch_bounds__(256)
void final_kernel(const float* __restrict__ gsum, const float* __restrict__ out_w,
                  const float* __restrict__ op_w, const float* __restrict__ op_b,
                  float* __restrict__ out)
{
    __shared__ float gs[1024];
    __shared__ float embd[512];
    int b = blockIdx.x, tid = threadIdx.x;
    for (int i = tid; i < 1024; i += 256) {
        int dd = i >> 9, c = i & 511;
        gs[i] = gsum[(dd * 4 + b) * 512 + c];
    }
    __syncthreads();
    for (int j = tid; j < 512; j += 256) {
        int dd = j >> 8, jj = j & 255;
        const float* wp = out_w + (size_t)(dd * 256 + jj) * 512;
        const float* gp = gs + dd * 512;
        float s = 0.f;
        for (int c = 0; c < 512; ++c) s = fmaf(gp[c], wp[c], s);
        embd[j] = s * (1.0f / 2048.0f);
    }
    __syncthreads();
    {
        int i = tid;
        float s = op_b[i];
        const float* wp = op_w + (size_t)i * 512;
        for (int j = 0; j < 512; ++j) s = fmaf(embd[j], wp[j], s);
        out[b * 256 + i] = s;
    }
}

// ---------------------------------------------------------------------------
extern "C" void kernel_launch(void* const* d_in, const int* in_sizes, int n_in,
                              void* d_out, int out_size, void* d_ws, size_t ws_size,
                              hipStream_t stream)
{
    (void)in_sizes; (void)n_in; (void)out_size; (void)ws_size;
    const float* x       = (const float*)d_in[0];   // [4,2048,512]
    const float* ip_w    = (const float*)d_in[1];   // [256,512]
    const float* ip_b    = (const float*)d_in[2];   // [256]
    const float* in_w    = (const float*)d_in[3];   // [2,1024,256]
    const float* conv_w  = (const float*)d_in[4];   // [2,512,4]
    const float* conv_b  = (const float*)d_in[5];   // [2,512]
    const float* xproj_w = (const float*)d_in[6];   // [2,48,512]
    const float* dt_w    = (const float*)d_in[7];   // [2,512,16]
    const float* dt_b    = (const float*)d_in[8];   // [2,512]
    const float* A_log   = (const float*)d_in[9];   // [2,512,16]
    const float* Dp      = (const float*)d_in[10];  // [2,512]
    const float* out_w   = (const float*)d_in[11];  // [2,256,512]
    const float* op_w    = (const float*)d_in[12];  // [256,512]
    const float* op_b    = (const float*)d_in[13];  // [256]
    float* out = (float*)d_out;                     // [4,256]

    // Workspace (bf16 intermediates, 51,920,896 B total):
    //   xz   [0,          33554432)  [2][8192][1024] bf16
    //   ubuf [33554432,   50331648)  [2][8192][512]  bf16  (written step 3)
    //   hbuf [33554432,   37748736)  [8192][256]     bf16  (ALIAS inside ubuf;
    //                                 dead after step 2, before ubuf is written)
    //   dbc  [50331648,   51904512)  [2][8192][48]   bf16
    //   gsum [51904512,   51920896)  [8][512]        fp32
    // dt is written in-place over xi (cols 0:512 of xz) after conv consumed xi.
    char* ws = (char*)d_ws;
    u16*   xz   = (u16*)(ws + 0);
    u16*   ubuf = (u16*)(ws + 33554432);
    u16*   hbuf = (u16*)(ws + 33554432);
    u16*   dbc  = (u16*)(ws + 50331648);
    float* gsum = (float*)(ws + 51904512);

    dim3 blk(256);

    // 1) in_proj: h = x @ ip_w^T + ip_b   [8192,256], A fp32
    gemm_bf16<0, 1><<<dim3(4, 128), blk, 0, stream>>>(
        x, ip_w, ip_b, hbuf, 8192, 256, 512, 512, 512, 256, 0);

    // 2) xz[d] = h(_flip) @ in_w[d]^T     [8192,1024] x2, A bf16
    for (int d = 0; d < 2; ++d)
        gemm_bf16<0, 0><<<dim3(16, 128), blk, 0, stream>>>(
            hbuf, in_w + (size_t)d * 1024 * 256, nullptr,
            xz + (size_t)d * 8192 * 1024,
            8192, 1024, 256, 256, 256, 1024, d);

    // 3) u = silu(causal_conv(xi) + cb)   (overwrites hbuf region — hbuf now dead)
    conv_silu_kernel<<<dim3(4096), blk, 0, stream>>>(xz, conv_w, conv_b, ubuf);

    // 4) dbc[d] = u[d] @ xproj_w[d]^T     [8192,48] x2, A bf16
    for (int d = 0; d < 2; ++d)
        gemm_bf16<0, 0><<<dim3(1, 128), blk, 0, stream>>>(
            ubuf + (size_t)d * 8192 * 512, xproj_w + (size_t)d * 48 * 512, nullptr,
            dbc + (size_t)d * 8192 * 48,
            8192, 48, 512, 512, 512, 48, 0);

    // 5) dt[d] = softplus(dbc[:,0:16] @ dt_w[d]^T + dt_b[d])  -> stored over xi cols
    for (int d = 0; d < 2; ++d)
        gemm_bf16<1, 0><<<dim3(8, 128), blk, 0, stream>>>(
            dbc + (size_t)d * 8192 * 48, dt_w + (size_t)d * 512 * 16,
            dt_b + (size_t)d * 512,
            xz + (size_t)d * 8192 * 1024,
            8192, 512, 16, 48, 16, 1024, 0);

    // 6) scan + gated mean-pool accumulation
    scan_kernel<<<dim3(256), blk, 0, stream>>>(xz, ubuf, dbc, A_log, Dp, gsum);

    // 7) projections to output
    final_kernel<<<dim3(4), blk, 0, stream>>>(gsum, out_w, op_w, op_b, out);
}

// Round 4
// 755.485 us; speedup vs baseline: 1.2097x; 1.2097x over previous
//
#include <hip/hip_runtime.h>
#include <stdint.h>

// MambaEncoder on MI355X (gfx950).
// ALL inputs and the output are FLOAT32. Intermediates bf16 in workspace,
// TIME-MAJOR (transposed: [ch][t]) so the scan/conv read contiguous vectors.
// GEMMs: bf16 MFMA, fp32 accum. Scan: chunked associative scan, 64 chunks/wave.
// Shapes: B=4, L=2048, d_model=512, hidden=256, d_inner=512, N=16, dt_rank=16, 2 dirs.

typedef unsigned short u16;
typedef __bf16 bf16x8 __attribute__((ext_vector_type(8)));
typedef float f32x4 __attribute__((ext_vector_type(4)));

__device__ __forceinline__ float b2f(u16 h) {
    union { unsigned int u; float f; } c; c.u = ((unsigned int)h) << 16; return c.f;
}
__device__ __forceinline__ u16 f2b(float f) {   // round-to-nearest-even
    union { float f; unsigned int u; } c; c.f = f;
    unsigned int r = c.u + 0x7FFFu + ((c.u >> 16) & 1u);
    return (u16)(r >> 16);
}

// ---------------------------------------------------------------------------
// bf16-MFMA GEMM: C = act(A @ W^T + bias), A[M,K], W[N,K] fp32, BM=BN=64, BK=32.
// AF32:   A is fp32 global input (else bf16 u16 intermediate).
// ATRANS: A stored transposed [K][M] with row length lda (K%32==0, no flip).
// CTRANS: store C transposed: CT[n][m], row length ldc (N%64==0).
// ACT: 0 none, 1 softplus. flip: A row (b,l)->(b,2047-l), L=2048.
// ---------------------------------------------------------------------------
template<int ACT, int AF32, int ATRANS, int CTRANS>
__global__ __launch_bounds__(256)
void gemm_bf16(const void* __restrict__ Av, const float* __restrict__ W,
               const float* __restrict__ bias, u16* __restrict__ C,
               int M, int N, int K, int lda, int ldw, int ldc, int flip)
{
    __shared__ u16 As[64 * 40];   // [m][k], pad 40: 2-way bank alias (free)
    __shared__ u16 Ws[64 * 40];   // [n][k]
    const int tid  = threadIdx.x;
    const int n0   = blockIdx.x * 64;
    const int m0   = blockIdx.y * 64;
    const int r    = tid >> 2;      // staging row 0..63
    const int seg  = tid & 3;       // 8-elem segment 0..3
    const int w    = tid >> 6;      // wave 0..3
    const int lane = tid & 63;
    const int r16  = lane & 15;
    const int q    = lane >> 4;     // quad 0..3

    f32x4 acc[4];
    #pragma unroll
    for (int i = 0; i < 4; ++i) acc[i] = (f32x4){0.f, 0.f, 0.f, 0.f};

    const int KT = (K + 31) >> 5;
    for (int kt = 0; kt < KT; ++kt) {
        const int kk = (kt << 5) + seg * 8;
        // --- stage A tile As[m][k] ---
        if (ATRANS) {
            // A is [K][M]: thread reads 8 m-values of one k-row, scatters to As.
            int k  = tid >> 3;          // 0..31
            int sg = tid & 7;           // 0..7
            const u16* sp = (const u16*)Av + (size_t)((kt << 5) + k) * lda + m0 + sg * 8;
            uint4 v = *(const uint4*)sp;
            const u16* vs = (const u16*)&v;
            #pragma unroll
            for (int e = 0; e < 8; ++e) As[(sg * 8 + e) * 40 + k] = vs[e];
        } else {
            int m   = m0 + r;           // M % 64 == 0: always valid
            int src = flip ? ((m & ~2047) | (2047 - (m & 2047))) : m;
            union { u16 s[8]; uint4 v; } t;
            if (AF32) {
                const float* sp = (const float*)Av + (size_t)src * lda;
                if (kk + 8 <= K) {
                    float4 f0 = *(const float4*)(sp + kk);
                    float4 f1 = *(const float4*)(sp + kk + 4);
                    t.s[0] = f2b(f0.x); t.s[1] = f2b(f0.y);
                    t.s[2] = f2b(f0.z); t.s[3] = f2b(f0.w);
                    t.s[4] = f2b(f1.x); t.s[5] = f2b(f1.y);
                    t.s[6] = f2b(f1.z); t.s[7] = f2b(f1.w);
                } else {
                    #pragma unroll
                    for (int e = 0; e < 8; ++e)
                        t.s[e] = ((kk + e) < K) ? f2b(sp[kk + e]) : (u16)0;
                }
            } else {
                const u16* sp = (const u16*)Av + (size_t)src * lda;
                if (kk + 8 <= K) {
                    t.v = *(const uint4*)(sp + kk);
                } else {
                    #pragma unroll
                    for (int e = 0; e < 8; ++e)
                        t.s[e] = ((kk + e) < K) ? sp[kk + e] : (u16)0;
                }
            }
            *(uint4*)(&As[r * 40 + seg * 8]) = t.v;
        }
        // --- stage W row n (fp32 -> bf16) ---
        {
            int n = n0 + r;
            const float* sp = W + (size_t)n * ldw;
            union { u16 s[8]; uint4 v; } t;
            if (n < N && kk + 8 <= K) {
                float4 f0 = *(const float4*)(sp + kk);
                float4 f1 = *(const float4*)(sp + kk + 4);
                t.s[0] = f2b(f0.x); t.s[1] = f2b(f0.y);
                t.s[2] = f2b(f0.z); t.s[3] = f2b(f0.w);
                t.s[4] = f2b(f1.x); t.s[5] = f2b(f1.y);
                t.s[6] = f2b(f1.z); t.s[7] = f2b(f1.w);
            } else {
                #pragma unroll
                for (int e = 0; e < 8; ++e)
                    t.s[e] = (n < N && (kk + e) < K) ? f2b(sp[kk + e]) : (u16)0;
            }
            *(uint4*)(&Ws[r * 40 + seg * 8]) = t.v;
        }
        __syncthreads();
        // A-frag: A[m=lane&15][k=quad*8+j]; B-frag: B[k][n=lane&15] = W[n][k]
        bf16x8 af = *(const bf16x8*)(&As[(w * 16 + r16) * 40 + q * 8]);
        #pragma unroll
        for (int nt = 0; nt < 4; ++nt) {
            bf16x8 wf = *(const bf16x8*)(&Ws[(nt * 16 + r16) * 40 + q * 8]);
            acc[nt] = __builtin_amdgcn_mfma_f32_16x16x32_bf16(af, wf, acc[nt], 0, 0, 0);
        }
        __syncthreads();
    }
    // epilogue: D[row=q*4+rg (m), col=r16 (n)]
    #pragma unroll
    for (int nt = 0; nt < 4; ++nt) {
        int n = n0 + nt * 16 + r16;
        if (n >= N) continue;
        float bv = bias ? bias[n] : 0.f;
        if (CTRANS) {
            union { u16 s[4]; uint2 v; } pk;
            #pragma unroll
            for (int rg = 0; rg < 4; ++rg) {
                float v = acc[nt][rg] + bv;
                if (ACT == 1) v = (v > 20.f) ? v : __logf(1.f + __expf(v));
                pk.s[rg] = f2b(v);
            }
            *(uint2*)(C + (size_t)n * ldc + m0 + w * 16 + q * 4) = pk.v;
        } else {
            #pragma unroll
            for (int rg = 0; rg < 4; ++rg) {
                int m = m0 + w * 16 + q * 4 + rg;
                float v = acc[nt][rg] + bv;
                if (ACT == 1) v = (v > 20.f) ? v : __logf(1.f + __expf(v));
                C[(size_t)m * ldc + n] = f2b(v);
            }
        }
    }
}

// ---------------------------------------------------------------------------
// Depthwise causal conv (4 taps) + silu, time-major.
// xzT [2][1024][8192]: xi rows 0:512 per dir. uT [2][512][8192].
// Thread: (d, ch, b, tile) — 32 outputs along t from a 40-value window.
// ---------------------------------------------------------------------------
__global__ __launch_bounds__(256)
void conv_silu_T(const u16* __restrict__ xzT, const float* __restrict__ cw,
                 const float* __restrict__ cb, u16* __restrict__ uT)
{
    int g    = blockIdx.x * 256 + threadIdx.x;
    int tile = g & 63;
    int b    = (g >> 6) & 3;
    int ch   = (g >> 8) & 511;
    int d    = g >> 17;
    int l0   = tile * 32;
    const u16* row = xzT + ((size_t)d * 1024 + ch) * 8192 + b * 2048;

    union { u16 s[40]; uint4 v[5]; } wd;
    wd.v[0] = (tile > 0) ? *(const uint4*)(row + l0 - 8) : (uint4){0, 0, 0, 0};
    #pragma unroll
    for (int i = 0; i < 4; ++i) wd.v[1 + i] = *(const uint4*)(row + l0 + i * 8);

    const float* wp = cw + (size_t)(d * 512 + ch) * 4;
    float c0 = wp[0], c1 = wp[1], c2 = wp[2], c3 = wp[3];
    float bias = cb[d * 512 + ch];

    union { u16 s[32]; uint4 v[4]; } o;
    #pragma unroll
    for (int i = 0; i < 32; ++i) {
        float acc = bias + c0 * b2f(wd.s[5 + i]) + c1 * b2f(wd.s[6 + i])
                         + c2 * b2f(wd.s[7 + i]) + c3 * b2f(wd.s[8 + i]);
        o.s[i] = f2b(acc / (1.f + __expf(-acc)));
    }
    u16* orow = uT + ((size_t)d * 512 + ch) * 8192 + b * 2048 + l0;
    #pragma unroll
    for (int i = 0; i < 4; ++i) ((uint4*)orow)[i] = o.v[i];
}

// ---------------------------------------------------------------------------
// Chunked associative scan. Wave = one (d,b,ch): 64 lanes = 64 chunks x 32 steps.
// Thread holds all 16 states. Phase 1: per-chunk affine map (P[16],S[16]).
// Hillis-Steele wave prefix with (P1,S1)o(P2,S2)=(P1P2, P2*S1+S2).
// Phase 2: replay with true start state; gacc = sum_t (y+u*D)*silu(z).
// dtT lives in xzT rows 0:512 (overwrote xi), z rows 512:1024. B/C from dbc rows.
// ---------------------------------------------------------------------------
__global__ __launch_bounds__(256, 4)
void scan_kernel(const u16* __restrict__ xzT, const u16* __restrict__ uT,
                 const u16* __restrict__ dbc, const float* __restrict__ A_log,
                 const float* __restrict__ Dp, float* __restrict__ gsum)
{
    const int wv   = threadIdx.x >> 6;
    const int lane = threadIdx.x & 63;        // chunk index
    const int blk  = blockIdx.x;              // 0..1023
    const int bd   = blk >> 7;                // d*4+b
    const int d    = bd >> 2, b = bd & 3;
    const int ch   = (blk & 127) * 4 + wv;

    const u16* pdt = xzT + ((size_t)d * 1024 + ch) * 8192 + b * 2048 + lane * 32;
    const u16* pz  = xzT + ((size_t)d * 1024 + 512 + ch) * 8192 + b * 2048 + lane * 32;
    const u16* pu  = uT + ((size_t)d * 512 + ch) * 8192 + b * 2048 + lane * 32;
    const u16* pBC = dbc + ((size_t)d * 8192 + b * 2048 + lane * 32) * 48;

    float a[16];
    #pragma unroll
    for (int n = 0; n < 16; ++n) a[n] = -__expf(A_log[(d * 512 + ch) * 16 + n]);
    const float Dv = Dp[d * 512 + ch];

    // ---- phase 1: chunk-local affine map ----
    float P[16], S[16];
    #pragma unroll
    for (int n = 0; n < 16; ++n) { P[n] = 1.f; S[n] = 0.f; }
    for (int gq = 0; gq < 4; ++gq) {
        uint4 vdt = *(const uint4*)(pdt + gq * 8);
        uint4 vu  = *(const uint4*)(pu + gq * 8);
        const u16* ds = (const u16*)&vdt;
        const u16* us = (const u16*)&vu;
        #pragma unroll
        for (int s = 0; s < 8; ++s) {
            int t = gq * 8 + s;
            float dt = b2f(ds[s]), uv = b2f(us[s]);
            uint4 b0 = *(const uint4*)(pBC + t * 48 + 16);
            uint4 b1 = *(const uint4*)(pBC + t * 48 + 24);
            const u16* Bs0 = (const u16*)&b0;
            const u16* Bs1 = (const u16*)&b1;
            float du = dt * uv;
            #pragma unroll
            for (int n = 0; n < 16; ++n) {
                float dA = __expf(dt * a[n]);
                float Bn = b2f(n < 8 ? Bs0[n] : Bs1[n - 8]);
                S[n] = fmaf(dA, S[n], du * Bn);
                P[n] *= dA;
            }
        }
    }
    // ---- wave inclusive prefix on (P,S) ----
    #pragma unroll
    for (int off = 1; off < 64; off <<= 1) {
        #pragma unroll
        for (int n = 0; n < 16; ++n) {
            float Pp = __shfl_up(P[n], off);
            float Sp = __shfl_up(S[n], off);
            Pp = (lane >= off) ? Pp : 1.f;
            Sp = (lane >= off) ? Sp : 0.f;
            S[n] = fmaf(P[n], Sp, S[n]);
            P[n] *= Pp;
        }
    }
    // start state = exclusive prefix
    float h[16];
    #pragma unroll
    for (int n = 0; n < 16; ++n) {
        float Hs = __shfl_up(S[n], 1);
        h[n] = (lane == 0) ? 0.f : Hs;
    }
    // ---- phase 2: replay with true state, accumulate gated mean-pool ----
    float gacc = 0.f;
    for (int gq = 0; gq < 4; ++gq) {
        uint4 vdt = *(const uint4*)(pdt + gq * 8);
        uint4 vu  = *(const uint4*)(pu + gq * 8);
        uint4 vz  = *(const uint4*)(pz + gq * 8);
        const u16* ds = (const u16*)&vdt;
        const u16* us = (const u16*)&vu;
        const u16* zs = (const u16*)&vz;
        #pragma unroll
        for (int s = 0; s < 8; ++s) {
            int t = gq * 8 + s;
            float dt = b2f(ds[s]), uv = b2f(us[s]), zv = b2f(zs[s]);
            uint4 b0 = *(const uint4*)(pBC + t * 48 + 16);
            uint4 b1 = *(const uint4*)(pBC + t * 48 + 24);
            uint4 c0 = *(const uint4*)(pBC + t * 48 + 32);
            uint4 c1 = *(const uint4*)(pBC + t * 48 + 40);
            const u16* Bs0 = (const u16*)&b0;
            const u16* Bs1 = (const u16*)&b1;
            const u16* Cs0 = (const u16*)&c0;
            const u16* Cs1 = (const u16*)&c1;
            float du = dt * uv;
            float p0 = 0.f, p1 = 0.f, p2 = 0.f, p3 = 0.f;
            #pragma unroll
            for (int n = 0; n < 16; ++n) {
                float dA = __expf(dt * a[n]);
                float Bn = b2f(n < 8 ? Bs0[n] : Bs1[n - 8]);
                float Cn = b2f(n < 8 ? Cs0[n] : Cs1[n - 8]);
                h[n] = fmaf(dA, h[n], du * Bn);
                if ((n & 3) == 0)      p0 = fmaf(h[n], Cn, p0);
                else if ((n & 3) == 1) p1 = fmaf(h[n], Cn, p1);
                else if ((n & 3) == 2) p2 = fmaf(h[n], Cn, p2);
                else                   p3 = fmaf(h[n], Cn, p3);
            }
            float p = (p0 + p1) + (p2 + p3);
            float sz = zv / (1.f + __expf(-zv));
            gacc = fmaf(p + uv * Dv, sz, gacc);
        }
    }
    // wave reduce gacc over 64 chunks
    #pragma unroll
    for (int off = 1; off < 64; off <<= 1) gacc += __shfl_xor(gacc, off);
    if (lane == 0) gsum[bd * 512 + ch] = gacc;
}

// ---------------------------------------------------------------------------
// Epilogue: gbar = gsum/L; embd[512] = concat_d(gbar[d] @ out_w[d]^T);
// out[b,i] = embd @ op_w[i,:]^T + op_b[i]  (all fp32). One block per batch b.
// ---------------------------------------------------------------------------
__global__ __launch_bounds__(256)
void final_kernel(const float* __restrict__ gsum, const float* __restrict__ out_w,
                  const float* __restrict__ op_w, const float* __restrict__ op_b,
                  float* __restrict__ out)
{
    __shared__ float gs[1024];
    __shared__ float embd[512];
    int b = blockIdx.x, tid = threadIdx.x;
    for (int i = tid; i < 1024; i += 256) {
        int dd = i >> 9, c = i & 511;
        gs[i] = gsum[(dd * 4 + b) * 512 + c];
    }
    __syncthreads();
    for (int j = tid; j < 512; j += 256) {
        int dd = j >> 8, jj = j & 255;
        const float* wp = out_w + (size_t)(dd * 256 + jj) * 512;
        const float* gp = gs + dd * 512;
        float s = 0.f;
        for (int c = 0; c < 512; ++c) s = fmaf(gp[c], wp[c], s);
        embd[j] = s * (1.0f / 2048.0f);
    }
    __syncthreads();
    {
        int i = tid;
        float s = op_b[i];
        const float* wp = op_w + (size_t)i * 512;
        for (int j = 0; j < 512; ++j) s = fmaf(embd[j], wp[j], s);
        out[b * 256 + i] = s;
    }
}

// ---------------------------------------------------------------------------
extern "C" void kernel_launch(void* const* d_in, const int* in_sizes, int n_in,
                              void* d_out, int out_size, void* d_ws, size_t ws_size,
                              hipStream_t stream)
{
    (void)in_sizes; (void)n_in; (void)out_size; (void)ws_size;
    const float* x       = (const float*)d_in[0];   // [4,2048,512]
    const float* ip_w    = (const float*)d_in[1];   // [256,512]
    const float* ip_b    = (const float*)d_in[2];   // [256]
    const float* in_w    = (const float*)d_in[3];   // [2,1024,256]
    const float* conv_w  = (const float*)d_in[4];   // [2,512,4]
    const float* conv_b  = (const float*)d_in[5];   // [2,512]
    const float* xproj_w = (const float*)d_in[6];   // [2,48,512]
    const float* dt_w    = (const float*)d_in[7];   // [2,512,16]
    const float* dt_b    = (const float*)d_in[8];   // [2,512]
    const float* A_log   = (const float*)d_in[9];   // [2,512,16]
    const float* Dp      = (const float*)d_in[10];  // [2,512]
    const float* out_w   = (const float*)d_in[11];  // [2,256,512]
    const float* op_w    = (const float*)d_in[12];  // [256,512]
    const float* op_b    = (const float*)d_in[13];  // [256]
    float* out = (float*)d_out;                     // [4,256]

    // Workspace (51,920,896 B):
    //   xzT  [0,        33554432)  [2][1024][8192] bf16, time-major; rows 0:512
    //                              = xi (later overwritten by dtT), 512:1024 = z
    //   uT   [33554432, 50331648)  [2][512][8192]  bf16, time-major (step 3)
    //   hbuf [33554432, 37748736)  [8192][256]     bf16 row-major (ALIAS in uT;
    //                              dead after step 2, before uT is written)
    //   dbc  [50331648, 51904512)  [2][8192][48]   bf16 row-major
    //   gsum [51904512, 51920896)  [8][512]        fp32
    char* ws = (char*)d_ws;
    u16*   xzT  = (u16*)(ws + 0);
    u16*   uT   = (u16*)(ws + 33554432);
    u16*   hbuf = (u16*)(ws + 33554432);
    u16*   dbc  = (u16*)(ws + 50331648);
    float* gsum = (float*)(ws + 51904512);

    dim3 blk(256);

    // 1) in_proj: hbuf = x @ ip_w^T + ip_b   [8192,256] row-major
    gemm_bf16<0, 1, 0, 0><<<dim3(4, 128), blk, 0, stream>>>(
        x, ip_w, ip_b, hbuf, 8192, 256, 512, 512, 512, 256, 0);

    // 2) xzT[d] = (hbuf(_flip) @ in_w[d]^T)^T   [1024][8192] x2
    for (int d = 0; d < 2; ++d)
        gemm_bf16<0, 0, 0, 1><<<dim3(16, 128), blk, 0, stream>>>(
            hbuf, in_w + (size_t)d * 1024 * 256, nullptr,
            xzT + (size_t)d * 1024 * 8192,
            8192, 1024, 256, 256, 256, 8192, d);

    // 3) uT = silu(causal_conv(xiT) + cb)   (hbuf region now dead)
    conv_silu_T<<<dim3(1024), blk, 0, stream>>>(xzT, conv_w, conv_b, uT);

    // 4) dbc[d] = (uT[d])^T @ xproj_w[d]^T   [8192,48] row-major x2 (A transposed)
    for (int d = 0; d < 2; ++d)
        gemm_bf16<0, 0, 1, 0><<<dim3(1, 128), blk, 0, stream>>>(
            uT + (size_t)d * 512 * 8192, xproj_w + (size_t)d * 48 * 512, nullptr,
            dbc + (size_t)d * 8192 * 48,
            8192, 48, 512, 8192, 512, 48, 0);

    // 5) dtT[d] = softplus(dbc[:,0:16] @ dt_w[d]^T + dt_b[d])^T -> xzT rows 0:512
    for (int d = 0; d < 2; ++d)
        gemm_bf16<1, 0, 0, 1><<<dim3(8, 128), blk, 0, stream>>>(
            dbc + (size_t)d * 8192 * 48, dt_w + (size_t)d * 512 * 16,
            dt_b + (size_t)d * 512,
            xzT + (size_t)d * 1024 * 8192,
            8192, 512, 16, 48, 16, 8192, 0);

    // 6) chunked scan + gated mean-pool accumulation
    scan_kernel<<<dim3(1024), blk, 0, stream>>>(xzT, uT, dbc, A_log, Dp, gsum);

    // 7) projections to output
    final_kernel<<<dim3(4), blk, 0, stream>>>(gsum, out_w, op_w, op_b, out);
}

// Round 5
// 368.881 us; speedup vs baseline: 2.4775x; 2.0480x over previous
//
#include <hip/hip_runtime.h>
#include <stdint.h>

// MambaEncoder on MI355X (gfx950).
// ALL inputs and the output are FLOAT32. Intermediates bf16 in workspace,
// TIME-MAJOR (transposed: [ch][t]) so the scan/conv read contiguous vectors.
// GEMMs: bf16 MFMA, fp32 accum. Scan: chunked associative scan, 64 chunks/wave.
// Shapes: B=4, L=2048, d_model=512, hidden=256, d_inner=512, N=16, dt_rank=16, 2 dirs.

typedef unsigned short u16;
typedef __bf16 bf16x8 __attribute__((ext_vector_type(8)));
typedef float f32x4 __attribute__((ext_vector_type(4)));

__device__ __forceinline__ float b2f(u16 h) {
    union { unsigned int u; float f; } c; c.u = ((unsigned int)h) << 16; return c.f;
}
__device__ __forceinline__ u16 f2b(float f) {   // round-to-nearest-even
    union { float f; unsigned int u; } c; c.f = f;
    unsigned int r = c.u + 0x7FFFu + ((c.u >> 16) & 1u);
    return (u16)(r >> 16);
}

// ---------------------------------------------------------------------------
// bf16-MFMA GEMM: C = act(A @ W^T + bias), A[M,K], W[N,K] fp32, BM=BN=64, BK=32.
// AF32:   A is fp32 global input (else bf16 u16 intermediate).
// ATRANS: A stored transposed [K][M] with row length lda (K%32==0, no flip).
// CTRANS: store C transposed: CT[n][m], row length ldc (N%64==0).
// ACT: 0 none, 1 softplus. flip: A row (b,l)->(b,2047-l), L=2048.
// ---------------------------------------------------------------------------
template<int ACT, int AF32, int ATRANS, int CTRANS>
__global__ __launch_bounds__(256)
void gemm_bf16(const void* __restrict__ Av, const float* __restrict__ W,
               const float* __restrict__ bias, u16* __restrict__ C,
               int M, int N, int K, int lda, int ldw, int ldc, int flip)
{
    __shared__ u16 As[64 * 40];   // [m][k], pad 40: 2-way bank alias (free)
    __shared__ u16 Ws[64 * 40];   // [n][k]
    const int tid  = threadIdx.x;
    const int n0   = blockIdx.x * 64;
    const int m0   = blockIdx.y * 64;
    const int r    = tid >> 2;      // staging row 0..63
    const int seg  = tid & 3;       // 8-elem segment 0..3
    const int w    = tid >> 6;      // wave 0..3
    const int lane = tid & 63;
    const int r16  = lane & 15;
    const int q    = lane >> 4;     // quad 0..3

    f32x4 acc[4];
    #pragma unroll
    for (int i = 0; i < 4; ++i) acc[i] = (f32x4){0.f, 0.f, 0.f, 0.f};

    const int KT = (K + 31) >> 5;
    for (int kt = 0; kt < KT; ++kt) {
        const int kk = (kt << 5) + seg * 8;
        // --- stage A tile As[m][k] ---
        if (ATRANS) {
            // A is [K][M]: thread reads 8 m-values of one k-row, scatters to As.
            int k  = tid >> 3;          // 0..31
            int sg = tid & 7;           // 0..7
            const u16* sp = (const u16*)Av + (size_t)((kt << 5) + k) * lda + m0 + sg * 8;
            uint4 v = *(const uint4*)sp;
            const u16* vs = (const u16*)&v;
            #pragma unroll
            for (int e = 0; e < 8; ++e) As[(sg * 8 + e) * 40 + k] = vs[e];
        } else {
            int m   = m0 + r;           // M % 64 == 0: always valid
            int src = flip ? ((m & ~2047) | (2047 - (m & 2047))) : m;
            union { u16 s[8]; uint4 v; } t;
            if (AF32) {
                const float* sp = (const float*)Av + (size_t)src * lda;
                if (kk + 8 <= K) {
                    float4 f0 = *(const float4*)(sp + kk);
                    float4 f1 = *(const float4*)(sp + kk + 4);
                    t.s[0] = f2b(f0.x); t.s[1] = f2b(f0.y);
                    t.s[2] = f2b(f0.z); t.s[3] = f2b(f0.w);
                    t.s[4] = f2b(f1.x); t.s[5] = f2b(f1.y);
                    t.s[6] = f2b(f1.z); t.s[7] = f2b(f1.w);
                } else {
                    #pragma unroll
                    for (int e = 0; e < 8; ++e)
                        t.s[e] = ((kk + e) < K) ? f2b(sp[kk + e]) : (u16)0;
                }
            } else {
                const u16* sp = (const u16*)Av + (size_t)src * lda;
                if (kk + 8 <= K) {
                    t.v = *(const uint4*)(sp + kk);
                } else {
                    #pragma unroll
                    for (int e = 0; e < 8; ++e)
                        t.s[e] = ((kk + e) < K) ? sp[kk + e] : (u16)0;
                }
            }
            *(uint4*)(&As[r * 40 + seg * 8]) = t.v;
        }
        // --- stage W row n (fp32 -> bf16) ---
        {
            int n = n0 + r;
            const float* sp = W + (size_t)n * ldw;
            union { u16 s[8]; uint4 v; } t;
            if (n < N && kk + 8 <= K) {
                float4 f0 = *(const float4*)(sp + kk);
                float4 f1 = *(const float4*)(sp + kk + 4);
                t.s[0] = f2b(f0.x); t.s[1] = f2b(f0.y);
                t.s[2] = f2b(f0.z); t.s[3] = f2b(f0.w);
                t.s[4] = f2b(f1.x); t.s[5] = f2b(f1.y);
                t.s[6] = f2b(f1.z); t.s[7] = f2b(f1.w);
            } else {
                #pragma unroll
                for (int e = 0; e < 8; ++e)
                    t.s[e] = (n < N && (kk + e) < K) ? f2b(sp[kk + e]) : (u16)0;
            }
            *(uint4*)(&Ws[r * 40 + seg * 8]) = t.v;
        }
        __syncthreads();
        // A-frag: A[m=lane&15][k=quad*8+j]; B-frag: B[k][n=lane&15] = W[n][k]
        bf16x8 af = *(const bf16x8*)(&As[(w * 16 + r16) * 40 + q * 8]);
        #pragma unroll
        for (int nt = 0; nt < 4; ++nt) {
            bf16x8 wf = *(const bf16x8*)(&Ws[(nt * 16 + r16) * 40 + q * 8]);
            acc[nt] = __builtin_amdgcn_mfma_f32_16x16x32_bf16(af, wf, acc[nt], 0, 0, 0);
        }
        __syncthreads();
    }
    // epilogue: D[row=q*4+rg (m), col=r16 (n)]
    #pragma unroll
    for (int nt = 0; nt < 4; ++nt) {
        int n = n0 + nt * 16 + r16;
        if (n >= N) continue;
        float bv = bias ? bias[n] : 0.f;
        if (CTRANS) {
            union { u16 s[4]; uint2 v; } pk;
            #pragma unroll
            for (int rg = 0; rg < 4; ++rg) {
                float v = acc[nt][rg] + bv;
                if (ACT == 1) v = (v > 20.f) ? v : __logf(1.f + __expf(v));
                pk.s[rg] = f2b(v);
            }
            *(uint2*)(C + (size_t)n * ldc + m0 + w * 16 + q * 4) = pk.v;
        } else {
            #pragma unroll
            for (int rg = 0; rg < 4; ++rg) {
                int m = m0 + w * 16 + q * 4 + rg;
                float v = acc[nt][rg] + bv;
                if (ACT == 1) v = (v > 20.f) ? v : __logf(1.f + __expf(v));
                C[(size_t)m * ldc + n] = f2b(v);
            }
        }
    }
}

// ---------------------------------------------------------------------------
// Depthwise causal conv (4 taps) + silu, time-major.
// xzT [2][1024][8192]: xi rows 0:512 per dir. uT [2][512][8192].
// Thread: (d, ch, b, tile) — 32 outputs along t from a 40-value window.
// ---------------------------------------------------------------------------
__global__ __launch_bounds__(256)
void conv_silu_T(const u16* __restrict__ xzT, const float* __restrict__ cw,
                 const float* __restrict__ cb, u16* __restrict__ uT)
{
    int g    = blockIdx.x * 256 + threadIdx.x;
    int tile = g & 63;
    int b    = (g >> 6) & 3;
    int ch   = (g >> 8) & 511;
    int d    = g >> 17;
    int l0   = tile * 32;
    const u16* row = xzT + ((size_t)d * 1024 + ch) * 8192 + b * 2048;

    union { u16 s[40]; uint4 v[5]; } wd;
    wd.v[0] = (tile > 0) ? *(const uint4*)(row + l0 - 8) : (uint4){0, 0, 0, 0};
    #pragma unroll
    for (int i = 0; i < 4; ++i) wd.v[1 + i] = *(const uint4*)(row + l0 + i * 8);

    const float* wp = cw + (size_t)(d * 512 + ch) * 4;
    float c0 = wp[0], c1 = wp[1], c2 = wp[2], c3 = wp[3];
    float bias = cb[d * 512 + ch];

    union { u16 s[32]; uint4 v[4]; } o;
    #pragma unroll
    for (int i = 0; i < 32; ++i) {
        float acc = bias + c0 * b2f(wd.s[5 + i]) + c1 * b2f(wd.s[6 + i])
                         + c2 * b2f(wd.s[7 + i]) + c3 * b2f(wd.s[8 + i]);
        o.s[i] = f2b(acc / (1.f + __expf(-acc)));
    }
    u16* orow = uT + ((size_t)d * 512 + ch) * 8192 + b * 2048 + l0;
    #pragma unroll
    for (int i = 0; i < 4; ++i) ((uint4*)orow)[i] = o.v[i];
}

// ---------------------------------------------------------------------------
// Chunked associative scan. Wave = one (d,b,ch): 64 lanes = 64 chunks x 32 steps.
// Thread holds all 16 states. Phase 1: per-chunk affine map (P[16],S[16]).
// Hillis-Steele wave prefix with (P1,S1)o(P2,S2)=(P1P2, P2*S1+S2).
// Phase 2: replay with true start state; gacc = sum_t (y+u*D)*silu(z).
// NOTE: __launch_bounds__(256) ONLY — a (256,4) min-waves clamp forced VGPR=64
// and spilled ~1.7 GB of scratch traffic (R4 counters: WRITE_SIZE 948 MB on a
// 16 KB-output kernel). Live set needs ~130 VGPRs.
// ---------------------------------------------------------------------------
__global__ __launch_bounds__(256)
void scan_kernel(const u16* __restrict__ xzT, const u16* __restrict__ uT,
                 const u16* __restrict__ dbc, const float* __restrict__ A_log,
                 const float* __restrict__ Dp, float* __restrict__ gsum)
{
    const int wv   = threadIdx.x >> 6;
    const int lane = threadIdx.x & 63;        // chunk index
    const int blk  = blockIdx.x;              // 0..1023
    const int bd   = blk >> 7;                // d*4+b
    const int d    = bd >> 2, b = bd & 3;
    const int ch   = (blk & 127) * 4 + wv;

    const u16* pdt = xzT + ((size_t)d * 1024 + ch) * 8192 + b * 2048 + lane * 32;
    const u16* pz  = xzT + ((size_t)d * 1024 + 512 + ch) * 8192 + b * 2048 + lane * 32;
    const u16* pu  = uT + ((size_t)d * 512 + ch) * 8192 + b * 2048 + lane * 32;
    const u16* pBC = dbc + ((size_t)d * 8192 + b * 2048 + lane * 32) * 48;

    float a[16];
    #pragma unroll
    for (int n = 0; n < 16; ++n) a[n] = -__expf(A_log[(d * 512 + ch) * 16 + n]);
    const float Dv = Dp[d * 512 + ch];

    // ---- phase 1: chunk-local affine map ----
    float P[16], S[16];
    #pragma unroll
    for (int n = 0; n < 16; ++n) { P[n] = 1.f; S[n] = 0.f; }
    for (int gq = 0; gq < 4; ++gq) {
        uint4 vdt = *(const uint4*)(pdt + gq * 8);
        uint4 vu  = *(const uint4*)(pu + gq * 8);
        const u16* ds = (const u16*)&vdt;
        const u16* us = (const u16*)&vu;
        #pragma unroll
        for (int s = 0; s < 8; ++s) {
            int t = gq * 8 + s;
            float dt = b2f(ds[s]), uv = b2f(us[s]);
            uint4 b0 = *(const uint4*)(pBC + t * 48 + 16);
            uint4 b1 = *(const uint4*)(pBC + t * 48 + 24);
            const u16* Bs0 = (const u16*)&b0;
            const u16* Bs1 = (const u16*)&b1;
            float du = dt * uv;
            #pragma unroll
            for (int n = 0; n < 16; ++n) {
                float dA = __expf(dt * a[n]);
                float Bn = b2f(n < 8 ? Bs0[n] : Bs1[n - 8]);
                S[n] = fmaf(dA, S[n], du * Bn);
                P[n] *= dA;
            }
        }
    }
    // ---- wave inclusive prefix on (P,S) ----
    #pragma unroll
    for (int off = 1; off < 64; off <<= 1) {
        #pragma unroll
        for (int n = 0; n < 16; ++n) {
            float Pp = __shfl_up(P[n], off);
            float Sp = __shfl_up(S[n], off);
            Pp = (lane >= off) ? Pp : 1.f;
            Sp = (lane >= off) ? Sp : 0.f;
            S[n] = fmaf(P[n], Sp, S[n]);
            P[n] *= Pp;
        }
    }
    // start state = exclusive prefix
    float h[16];
    #pragma unroll
    for (int n = 0; n < 16; ++n) {
        float Hs = __shfl_up(S[n], 1);
        h[n] = (lane == 0) ? 0.f : Hs;
    }
    // ---- phase 2: replay with true state, accumulate gated mean-pool ----
    float gacc = 0.f;
    for (int gq = 0; gq < 4; ++gq) {
        uint4 vdt = *(const uint4*)(pdt + gq * 8);
        uint4 vu  = *(const uint4*)(pu + gq * 8);
        uint4 vz  = *(const uint4*)(pz + gq * 8);
        const u16* ds = (const u16*)&vdt;
        const u16* us = (const u16*)&vu;
        const u16* zs = (const u16*)&vz;
        #pragma unroll
        for (int s = 0; s < 8; ++s) {
            int t = gq * 8 + s;
            float dt = b2f(ds[s]), uv = b2f(us[s]), zv = b2f(zs[s]);
            uint4 b0 = *(const uint4*)(pBC + t * 48 + 16);
            uint4 b1 = *(const uint4*)(pBC + t * 48 + 24);
            uint4 c0 = *(const uint4*)(pBC + t * 48 + 32);
            uint4 c1 = *(const uint4*)(pBC + t * 48 + 40);
            const u16* Bs0 = (const u16*)&b0;
            const u16* Bs1 = (const u16*)&b1;
            const u16* Cs0 = (const u16*)&c0;
            const u16* Cs1 = (const u16*)&c1;
            float du = dt * uv;
            float p0 = 0.f, p1 = 0.f, p2 = 0.f, p3 = 0.f;
            #pragma unroll
            for (int n = 0; n < 16; ++n) {
                float dA = __expf(dt * a[n]);
                float Bn = b2f(n < 8 ? Bs0[n] : Bs1[n - 8]);
                float Cn = b2f(n < 8 ? Cs0[n] : Cs1[n - 8]);
                h[n] = fmaf(dA, h[n], du * Bn);
                if ((n & 3) == 0)      p0 = fmaf(h[n], Cn, p0);
                else if ((n & 3) == 1) p1 = fmaf(h[n], Cn, p1);
                else if ((n & 3) == 2) p2 = fmaf(h[n], Cn, p2);
                else                   p3 = fmaf(h[n], Cn, p3);
            }
            float p = (p0 + p1) + (p2 + p3);
            float sz = zv / (1.f + __expf(-zv));
            gacc = fmaf(p + uv * Dv, sz, gacc);
        }
    }
    // wave reduce gacc over 64 chunks
    #pragma unroll
    for (int off = 1; off < 64; off <<= 1) gacc += __shfl_xor(gacc, off);
    if (lane == 0) gsum[bd * 512 + ch] = gacc;
}

// ---------------------------------------------------------------------------
// Epilogue: gbar = gsum/L; embd[512] = concat_d(gbar[d] @ out_w[d]^T);
// out[b,i] = embd @ op_w[i,:]^T + op_b[i]  (all fp32). One block per batch b.
// ---------------------------------------------------------------------------
__global__ __launch_bounds__(256)
void final_kernel(const float* __restrict__ gsum, const float* __restrict__ out_w,
                  const float* __restrict__ op_w, const float* __restrict__ op_b,
                  float* __restrict__ out)
{
    __shared__ float gs[1024];
    __shared__ float embd[512];
    int b = blockIdx.x, tid = threadIdx.x;
    for (int i = tid; i < 1024; i += 256) {
        int dd = i >> 9, c = i & 511;
        gs[i] = gsum[(dd * 4 + b) * 512 + c];
    }
    __syncthreads();
    for (int j = tid; j < 512; j += 256) {
        int dd = j >> 8, jj = j & 255;
        const float* wp = out_w + (size_t)(dd * 256 + jj) * 512;
        const float* gp = gs + dd * 512;
        float s = 0.f;
        for (int c = 0; c < 512; ++c) s = fmaf(gp[c], wp[c], s);
        embd[j] = s * (1.0f / 2048.0f);
    }
    __syncthreads();
    {
        int i = tid;
        float s = op_b[i];
        const float* wp = op_w + (size_t)i * 512;
        for (int j = 0; j < 512; ++j) s = fmaf(embd[j], wp[j], s);
        out[b * 256 + i] = s;
    }
}

// ---------------------------------------------------------------------------
extern "C" void kernel_launch(void* const* d_in, const int* in_sizes, int n_in,
                              void* d_out, int out_size, void* d_ws, size_t ws_size,
                              hipStream_t stream)
{
    (void)in_sizes; (void)n_in; (void)out_size; (void)ws_size;
    const float* x       = (const float*)d_in[0];   // [4,2048,512]
    const float* ip_w    = (const float*)d_in[1];   // [256,512]
    const float* ip_b    = (const float*)d_in[2];   // [256]
    const float* in_w    = (const float*)d_in[3];   // [2,1024,256]
    const float* conv_w  = (const float*)d_in[4];   // [2,512,4]
    const float* conv_b  = (const float*)d_in[5];   // [2,512]
    const float* xproj_w = (const float*)d_in[6];   // [2,48,512]
    const float* dt_w    = (const float*)d_in[7];   // [2,512,16]
    const float* dt_b    = (const float*)d_in[8];   // [2,512]
    const float* A_log   = (const float*)d_in[9];   // [2,512,16]
    const float* Dp      = (const float*)d_in[10];  // [2,512]
    const float* out_w   = (const float*)d_in[11];  // [2,256,512]
    const float* op_w    = (const float*)d_in[12];  // [256,512]
    const float* op_b    = (const float*)d_in[13];  // [256]
    float* out = (float*)d_out;                     // [4,256]

    // Workspace (51,920,896 B):
    //   xzT  [0,        33554432)  [2][1024][8192] bf16, time-major; rows 0:512
    //                              = xi (later overwritten by dtT), 512:1024 = z
    //   uT   [33554432, 50331648)  [2][512][8192]  bf16, time-major (step 3)
    //   hbuf [33554432, 37748736)  [8192][256]     bf16 row-major (ALIAS in uT;
    //                              dead after step 2, before uT is written)
    //   dbc  [50331648, 51904512)  [2][8192][48]   bf16 row-major
    //   gsum [51904512, 51920896)  [8][512]        fp32
    char* ws = (char*)d_ws;
    u16*   xzT  = (u16*)(ws + 0);
    u16*   uT   = (u16*)(ws + 33554432);
    u16*   hbuf = (u16*)(ws + 33554432);
    u16*   dbc  = (u16*)(ws + 50331648);
    float* gsum = (float*)(ws + 51904512);

    dim3 blk(256);

    // 1) in_proj: hbuf = x @ ip_w^T + ip_b   [8192,256] row-major
    gemm_bf16<0, 1, 0, 0><<<dim3(4, 128), blk, 0, stream>>>(
        x, ip_w, ip_b, hbuf, 8192, 256, 512, 512, 512, 256, 0);

    // 2) xzT[d] = (hbuf(_flip) @ in_w[d]^T)^T   [1024][8192] x2
    for (int d = 0; d < 2; ++d)
        gemm_bf16<0, 0, 0, 1><<<dim3(16, 128), blk, 0, stream>>>(
            hbuf, in_w + (size_t)d * 1024 * 256, nullptr,
            xzT + (size_t)d * 1024 * 8192,
            8192, 1024, 256, 256, 256, 8192, d);

    // 3) uT = silu(causal_conv(xiT) + cb)   (hbuf region now dead)
    conv_silu_T<<<dim3(1024), blk, 0, stream>>>(xzT, conv_w, conv_b, uT);

    // 4) dbc[d] = (uT[d])^T @ xproj_w[d]^T   [8192,48] row-major x2 (A transposed)
    for (int d = 0; d < 2; ++d)
        gemm_bf16<0, 0, 1, 0><<<dim3(1, 128), blk, 0, stream>>>(
            uT + (size_t)d * 512 * 8192, xproj_w + (size_t)d * 48 * 512, nullptr,
            dbc + (size_t)d * 8192 * 48,
            8192, 48, 512, 8192, 512, 48, 0);

    // 5) dtT[d] = softplus(dbc[:,0:16] @ dt_w[d]^T + dt_b[d])^T -> xzT rows 0:512
    for (int d = 0; d < 2; ++d)
        gemm_bf16<1, 0, 0, 1><<<dim3(8, 128), blk, 0, stream>>>(
            dbc + (size_t)d * 8192 * 48, dt_w + (size_t)d * 512 * 16,
            dt_b + (size_t)d * 512,
            xzT + (size_t)d * 1024 * 8192,
            8192, 512, 16, 48, 16, 8192, 0);

    // 6) chunked scan + gated mean-pool accumulation
    scan_kernel<<<dim3(1024), blk, 0, stream>>>(xzT, uT, dbc, A_log, Dp, gsum);

    // 7) projections to output
    final_kernel<<<dim3(4), blk, 0, stream>>>(gsum, out_w, op_w, op_b, out);
}

// Round 6
// 356.256 us; speedup vs baseline: 2.5653x; 1.0354x over previous
//
#include <hip/hip_runtime.h>
#include <stdint.h>

// MambaEncoder on MI355X (gfx950).
// ALL inputs and the output are FLOAT32. Intermediates bf16 in workspace,
// TIME-MAJOR (transposed: [ch][t]) so the scan/conv read contiguous vectors.
// GEMMs: bf16 MFMA, fp32 accum. Scan: single-pass chunked associative scan
// (gated sum decomposed as alpha + beta . h0 — no replay pass).
// Shapes: B=4, L=2048, d_model=512, hidden=256, d_inner=512, N=16, dt_rank=16, 2 dirs.

typedef unsigned short u16;
typedef __bf16 bf16x8 __attribute__((ext_vector_type(8)));
typedef float f32x4 __attribute__((ext_vector_type(4)));

__device__ __forceinline__ float b2f(u16 h) {
    union { unsigned int u; float f; } c; c.u = ((unsigned int)h) << 16; return c.f;
}
__device__ __forceinline__ u16 f2b(float f) {   // round-to-nearest-even
    union { float f; unsigned int u; } c; c.f = f;
    unsigned int r = c.u + 0x7FFFu + ((c.u >> 16) & 1u);
    return (u16)(r >> 16);
}

// ---------------------------------------------------------------------------
// bf16-MFMA GEMM: C = act(A @ W^T + bias), A[M,K], W[N,K] fp32, BM=BN=64, BK=32.
// AF32:   A is fp32 global input (else bf16 u16 intermediate).
// ATRANS: A stored transposed [K][M] with row length lda (K%32==0, no flip).
// CTRANS: store C transposed: CT[n][m], row length ldc (N%64==0).
// ACT: 0 none, 1 softplus. flip: A row (b,l)->(b,2047-l), L=2048.
// ---------------------------------------------------------------------------
template<int ACT, int AF32, int ATRANS, int CTRANS>
__global__ __launch_bounds__(256)
void gemm_bf16(const void* __restrict__ Av, const float* __restrict__ W,
               const float* __restrict__ bias, u16* __restrict__ C,
               int M, int N, int K, int lda, int ldw, int ldc, int flip)
{
    __shared__ u16 As[64 * 40];   // [m][k], pad 40: 2-way bank alias (free)
    __shared__ u16 Ws[64 * 40];   // [n][k]
    const int tid  = threadIdx.x;
    const int n0   = blockIdx.x * 64;
    const int m0   = blockIdx.y * 64;
    const int r    = tid >> 2;      // staging row 0..63
    const int seg  = tid & 3;       // 8-elem segment 0..3
    const int w    = tid >> 6;      // wave 0..3
    const int lane = tid & 63;
    const int r16  = lane & 15;
    const int q    = lane >> 4;     // quad 0..3

    f32x4 acc[4];
    #pragma unroll
    for (int i = 0; i < 4; ++i) acc[i] = (f32x4){0.f, 0.f, 0.f, 0.f};

    const int KT = (K + 31) >> 5;
    for (int kt = 0; kt < KT; ++kt) {
        const int kk = (kt << 5) + seg * 8;
        // --- stage A tile As[m][k] ---
        if (ATRANS) {
            // A is [K][M]: thread reads 8 m-values of one k-row, scatters to As.
            int k  = tid >> 3;          // 0..31
            int sg = tid & 7;           // 0..7
            const u16* sp = (const u16*)Av + (size_t)((kt << 5) + k) * lda + m0 + sg * 8;
            uint4 v = *(const uint4*)sp;
            const u16* vs = (const u16*)&v;
            #pragma unroll
            for (int e = 0; e < 8; ++e) As[(sg * 8 + e) * 40 + k] = vs[e];
        } else {
            int m   = m0 + r;           // M % 64 == 0: always valid
            int src = flip ? ((m & ~2047) | (2047 - (m & 2047))) : m;
            union { u16 s[8]; uint4 v; } t;
            if (AF32) {
                const float* sp = (const float*)Av + (size_t)src * lda;
                if (kk + 8 <= K) {
                    float4 f0 = *(const float4*)(sp + kk);
                    float4 f1 = *(const float4*)(sp + kk + 4);
                    t.s[0] = f2b(f0.x); t.s[1] = f2b(f0.y);
                    t.s[2] = f2b(f0.z); t.s[3] = f2b(f0.w);
                    t.s[4] = f2b(f1.x); t.s[5] = f2b(f1.y);
                    t.s[6] = f2b(f1.z); t.s[7] = f2b(f1.w);
                } else {
                    #pragma unroll
                    for (int e = 0; e < 8; ++e)
                        t.s[e] = ((kk + e) < K) ? f2b(sp[kk + e]) : (u16)0;
                }
            } else {
                const u16* sp = (const u16*)Av + (size_t)src * lda;
                if (kk + 8 <= K) {
                    t.v = *(const uint4*)(sp + kk);
                } else {
                    #pragma unroll
                    for (int e = 0; e < 8; ++e)
                        t.s[e] = ((kk + e) < K) ? sp[kk + e] : (u16)0;
                }
            }
            *(uint4*)(&As[r * 40 + seg * 8]) = t.v;
        }
        // --- stage W row n (fp32 -> bf16) ---
        {
            int n = n0 + r;
            const float* sp = W + (size_t)n * ldw;
            union { u16 s[8]; uint4 v; } t;
            if (n < N && kk + 8 <= K) {
                float4 f0 = *(const float4*)(sp + kk);
                float4 f1 = *(const float4*)(sp + kk + 4);
                t.s[0] = f2b(f0.x); t.s[1] = f2b(f0.y);
                t.s[2] = f2b(f0.z); t.s[3] = f2b(f0.w);
                t.s[4] = f2b(f1.x); t.s[5] = f2b(f1.y);
                t.s[6] = f2b(f1.z); t.s[7] = f2b(f1.w);
            } else {
                #pragma unroll
                for (int e = 0; e < 8; ++e)
                    t.s[e] = (n < N && (kk + e) < K) ? f2b(sp[kk + e]) : (u16)0;
            }
            *(uint4*)(&Ws[r * 40 + seg * 8]) = t.v;
        }
        __syncthreads();
        // A-frag: A[m=lane&15][k=quad*8+j]; B-frag: B[k][n=lane&15] = W[n][k]
        bf16x8 af = *(const bf16x8*)(&As[(w * 16 + r16) * 40 + q * 8]);
        #pragma unroll
        for (int nt = 0; nt < 4; ++nt) {
            bf16x8 wf = *(const bf16x8*)(&Ws[(nt * 16 + r16) * 40 + q * 8]);
            acc[nt] = __builtin_amdgcn_mfma_f32_16x16x32_bf16(af, wf, acc[nt], 0, 0, 0);
        }
        __syncthreads();
    }
    // epilogue: D[row=q*4+rg (m), col=r16 (n)]
    #pragma unroll
    for (int nt = 0; nt < 4; ++nt) {
        int n = n0 + nt * 16 + r16;
        if (n >= N) continue;
        float bv = bias ? bias[n] : 0.f;
        if (CTRANS) {
            union { u16 s[4]; uint2 v; } pk;
            #pragma unroll
            for (int rg = 0; rg < 4; ++rg) {
                float v = acc[nt][rg] + bv;
                if (ACT == 1) v = (v > 20.f) ? v : __logf(1.f + __expf(v));
                pk.s[rg] = f2b(v);
            }
            *(uint2*)(C + (size_t)n * ldc + m0 + w * 16 + q * 4) = pk.v;
        } else {
            #pragma unroll
            for (int rg = 0; rg < 4; ++rg) {
                int m = m0 + w * 16 + q * 4 + rg;
                float v = acc[nt][rg] + bv;
                if (ACT == 1) v = (v > 20.f) ? v : __logf(1.f + __expf(v));
                C[(size_t)m * ldc + n] = f2b(v);
            }
        }
    }
}

// ---------------------------------------------------------------------------
// Depthwise causal conv (4 taps) + silu, time-major.
// xzT [2][1024][8192]: xi rows 0:512 per dir. uT [2][512][8192].
// Thread: (d, ch, b, tile) — 32 outputs along t from a 40-value window.
// ---------------------------------------------------------------------------
__global__ __launch_bounds__(256)
void conv_silu_T(const u16* __restrict__ xzT, const float* __restrict__ cw,
                 const float* __restrict__ cb, u16* __restrict__ uT)
{
    int g    = blockIdx.x * 256 + threadIdx.x;
    int tile = g & 63;
    int b    = (g >> 6) & 3;
    int ch   = (g >> 8) & 511;
    int d    = g >> 17;
    int l0   = tile * 32;
    const u16* row = xzT + ((size_t)d * 1024 + ch) * 8192 + b * 2048;

    union { u16 s[40]; uint4 v[5]; } wd;
    wd.v[0] = (tile > 0) ? *(const uint4*)(row + l0 - 8) : (uint4){0, 0, 0, 0};
    #pragma unroll
    for (int i = 0; i < 4; ++i) wd.v[1 + i] = *(const uint4*)(row + l0 + i * 8);

    const float* wp = cw + (size_t)(d * 512 + ch) * 4;
    float c0 = wp[0], c1 = wp[1], c2 = wp[2], c3 = wp[3];
    float bias = cb[d * 512 + ch];

    union { u16 s[32]; uint4 v[4]; } o;
    #pragma unroll
    for (int i = 0; i < 32; ++i) {
        float acc = bias + c0 * b2f(wd.s[5 + i]) + c1 * b2f(wd.s[6 + i])
                         + c2 * b2f(wd.s[7 + i]) + c3 * b2f(wd.s[8 + i]);
        o.s[i] = f2b(acc / (1.f + __expf(-acc)));
    }
    u16* orow = uT + ((size_t)d * 512 + ch) * 8192 + b * 2048 + l0;
    #pragma unroll
    for (int i = 0; i < 4; ++i) ((uint4*)orow)[i] = o.v[i];
}

// ---------------------------------------------------------------------------
// Single-pass chunked associative scan. Wave = one (d,b,ch): 64 lanes = 64
// chunks x 32 steps. Per chunk, inclusive-local (P_t, S_t) give h_t = P_t*h0
// + S_t, so the gated mean-pool term splits linearly in h0:
//   sum_t g_t*(C_t.h_t + u_t*D) = alpha + beta . h0
//   alpha  = sum_t g_t*(C_t.S_t + u_t*D)
//   beta_n = sum_t g_t*C_{t,n}*P_{t,n}
// One data pass accumulates (P,S,alpha,beta); wave prefix on (P,S) yields h0;
// epilogue: gacc = alpha + beta.h0; wave-reduce. No replay (R5: replay was
// half the loads + half the exps).
// NOTE: no min-waves clamp — (256,4) forced VGPR=64 and spilled 1.7 GB (R4).
// ---------------------------------------------------------------------------
__global__ __launch_bounds__(256)
void scan_kernel(const u16* __restrict__ xzT, const u16* __restrict__ uT,
                 const u16* __restrict__ dbc, const float* __restrict__ A_log,
                 const float* __restrict__ Dp, float* __restrict__ gsum)
{
    const int wv   = threadIdx.x >> 6;
    const int lane = threadIdx.x & 63;        // chunk index
    const int blk  = blockIdx.x;              // 0..1023
    const int bd   = blk >> 7;                // d*4+b
    const int d    = bd >> 2, b = bd & 3;
    const int ch   = (blk & 127) * 4 + wv;

    const u16* pdt = xzT + ((size_t)d * 1024 + ch) * 8192 + b * 2048 + lane * 32;
    const u16* pz  = xzT + ((size_t)d * 1024 + 512 + ch) * 8192 + b * 2048 + lane * 32;
    const u16* pu  = uT + ((size_t)d * 512 + ch) * 8192 + b * 2048 + lane * 32;
    const u16* pBC = dbc + ((size_t)d * 8192 + b * 2048 + lane * 32) * 48;

    float a[16];
    #pragma unroll
    for (int n = 0; n < 16; ++n) a[n] = -__expf(A_log[(d * 512 + ch) * 16 + n]);
    const float Dv = Dp[d * 512 + ch];

    // ---- single pass: local (P,S) + gated accumulators (alpha, beta) ----
    float P[16], S[16], beta[16];
    #pragma unroll
    for (int n = 0; n < 16; ++n) { P[n] = 1.f; S[n] = 0.f; beta[n] = 0.f; }
    float alpha = 0.f;
    for (int gq = 0; gq < 4; ++gq) {
        uint4 vdt = *(const uint4*)(pdt + gq * 8);
        uint4 vu  = *(const uint4*)(pu + gq * 8);
        uint4 vz  = *(const uint4*)(pz + gq * 8);
        const u16* ds = (const u16*)&vdt;
        const u16* us = (const u16*)&vu;
        const u16* zs = (const u16*)&vz;
        #pragma unroll
        for (int s = 0; s < 8; ++s) {
            int t = gq * 8 + s;
            float dt = b2f(ds[s]), uv = b2f(us[s]), zv = b2f(zs[s]);
            uint4 b0 = *(const uint4*)(pBC + t * 48 + 16);
            uint4 b1 = *(const uint4*)(pBC + t * 48 + 24);
            uint4 c0 = *(const uint4*)(pBC + t * 48 + 32);
            uint4 c1 = *(const uint4*)(pBC + t * 48 + 40);
            const u16* Bs0 = (const u16*)&b0;
            const u16* Bs1 = (const u16*)&b1;
            const u16* Cs0 = (const u16*)&c0;
            const u16* Cs1 = (const u16*)&c1;
            float du = dt * uv;
            float g  = zv / (1.f + __expf(-zv));   // silu(z)
            float dotCS = 0.f;
            #pragma unroll
            for (int n = 0; n < 16; ++n) {
                float dA = __expf(dt * a[n]);
                float Bn = b2f(n < 8 ? Bs0[n] : Bs1[n - 8]);
                float Cn = b2f(n < 8 ? Cs0[n] : Cs1[n - 8]);
                S[n] = fmaf(dA, S[n], du * Bn);
                P[n] *= dA;
                float gC = g * Cn;
                dotCS = fmaf(Cn, S[n], dotCS);
                beta[n] = fmaf(gC, P[n], beta[n]);
            }
            alpha = fmaf(g, fmaf(uv, Dv, dotCS), alpha);
        }
    }
    // ---- wave inclusive prefix on (P,S) ----
    #pragma unroll
    for (int off = 1; off < 64; off <<= 1) {
        #pragma unroll
        for (int n = 0; n < 16; ++n) {
            float Pp = __shfl_up(P[n], off);
            float Sp = __shfl_up(S[n], off);
            Pp = (lane >= off) ? Pp : 1.f;
            Sp = (lane >= off) ? Sp : 0.f;
            S[n] = fmaf(P[n], Sp, S[n]);
            P[n] *= Pp;
        }
    }
    // ---- epilogue: gacc = alpha + beta . h0 (h0 = exclusive prefix) ----
    float gacc = alpha;
    #pragma unroll
    for (int n = 0; n < 16; ++n) {
        float Hs = __shfl_up(S[n], 1);
        float h0 = (lane == 0) ? 0.f : Hs;
        gacc = fmaf(beta[n], h0, gacc);
    }
    // wave reduce gacc over 64 chunks
    #pragma unroll
    for (int off = 1; off < 64; off <<= 1) gacc += __shfl_xor(gacc, off);
    if (lane == 0) gsum[bd * 512 + ch] = gacc;
}

// ---------------------------------------------------------------------------
// Epilogue: gbar = gsum/L; embd[512] = concat_d(gbar[d] @ out_w[d]^T);
// out[b,i] = embd @ op_w[i,:]^T + op_b[i]  (all fp32). One block per batch b.
// ---------------------------------------------------------------------------
__global__ __launch_bounds__(256)
void final_kernel(const float* __restrict__ gsum, const float* __restrict__ out_w,
                  const float* __restrict__ op_w, const float* __restrict__ op_b,
                  float* __restrict__ out)
{
    __shared__ float gs[1024];
    __shared__ float embd[512];
    int b = blockIdx.x, tid = threadIdx.x;
    for (int i = tid; i < 1024; i += 256) {
        int dd = i >> 9, c = i & 511;
        gs[i] = gsum[(dd * 4 + b) * 512 + c];
    }
    __syncthreads();
    for (int j = tid; j < 512; j += 256) {
        int dd = j >> 8, jj = j & 255;
        const float* wp = out_w + (size_t)(dd * 256 + jj) * 512;
        const float* gp = gs + dd * 512;
        float s = 0.f;
        for (int c = 0; c < 512; ++c) s = fmaf(gp[c], wp[c], s);
        embd[j] = s * (1.0f / 2048.0f);
    }
    __syncthreads();
    {
        int i = tid;
        float s = op_b[i];
        const float* wp = op_w + (size_t)i * 512;
        for (int j = 0; j < 512; ++j) s = fmaf(embd[j], wp[j], s);
        out[b * 256 + i] = s;
    }
}

// ---------------------------------------------------------------------------
extern "C" void kernel_launch(void* const* d_in, const int* in_sizes, int n_in,
                              void* d_out, int out_size, void* d_ws, size_t ws_size,
                              hipStream_t stream)
{
    (void)in_sizes; (void)n_in; (void)out_size; (void)ws_size;
    const float* x       = (const float*)d_in[0];   // [4,2048,512]
    const float* ip_w    = (const float*)d_in[1];   // [256,512]
    const float* ip_b    = (const float*)d_in[2];   // [256]
    const float* in_w    = (const float*)d_in[3];   // [2,1024,256]
    const float* conv_w  = (const float*)d_in[4];   // [2,512,4]
    const float* conv_b  = (const float*)d_in[5];   // [2,512]
    const float* xproj_w = (const float*)d_in[6];   // [2,48,512]
    const float* dt_w    = (const float*)d_in[7];   // [2,512,16]
    const float* dt_b    = (const float*)d_in[8];   // [2,512]
    const float* A_log   = (const float*)d_in[9];   // [2,512,16]
    const float* Dp      = (const float*)d_in[10];  // [2,512]
    const float* out_w   = (const float*)d_in[11];  // [2,256,512]
    const float* op_w    = (const float*)d_in[12];  // [256,512]
    const float* op_b    = (const float*)d_in[13];  // [256]
    float* out = (float*)d_out;                     // [4,256]

    // Workspace (51,920,896 B):
    //   xzT  [0,        33554432)  [2][1024][8192] bf16, time-major; rows 0:512
    //                              = xi (later overwritten by dtT), 512:1024 = z
    //   uT   [33554432, 50331648)  [2][512][8192]  bf16, time-major (step 3)
    //   hbuf [33554432, 37748736)  [8192][256]     bf16 row-major (ALIAS in uT;
    //                              dead after step 2, before uT is written)
    //   dbc  [50331648, 51904512)  [2][8192][48]   bf16 row-major
    //   gsum [51904512, 51920896)  [8][512]        fp32
    char* ws = (char*)d_ws;
    u16*   xzT  = (u16*)(ws + 0);
    u16*   uT   = (u16*)(ws + 33554432);
    u16*   hbuf = (u16*)(ws + 33554432);
    u16*   dbc  = (u16*)(ws + 50331648);
    float* gsum = (float*)(ws + 51904512);

    dim3 blk(256);

    // 1) in_proj: hbuf = x @ ip_w^T + ip_b   [8192,256] row-major
    gemm_bf16<0, 1, 0, 0><<<dim3(4, 128), blk, 0, stream>>>(
        x, ip_w, ip_b, hbuf, 8192, 256, 512, 512, 512, 256, 0);

    // 2) xzT[d] = (hbuf(_flip) @ in_w[d]^T)^T   [1024][8192] x2
    for (int d = 0; d < 2; ++d)
        gemm_bf16<0, 0, 0, 1><<<dim3(16, 128), blk, 0, stream>>>(
            hbuf, in_w + (size_t)d * 1024 * 256, nullptr,
            xzT + (size_t)d * 1024 * 8192,
            8192, 1024, 256, 256, 256, 8192, d);

    // 3) uT = silu(causal_conv(xiT) + cb)   (hbuf region now dead)
    conv_silu_T<<<dim3(1024), blk, 0, stream>>>(xzT, conv_w, conv_b, uT);

    // 4) dbc[d] = (uT[d])^T @ xproj_w[d]^T   [8192,48] row-major x2 (A transposed)
    for (int d = 0; d < 2; ++d)
        gemm_bf16<0, 0, 1, 0><<<dim3(1, 128), blk, 0, stream>>>(
            uT + (size_t)d * 512 * 8192, xproj_w + (size_t)d * 48 * 512, nullptr,
            dbc + (size_t)d * 8192 * 48,
            8192, 48, 512, 8192, 512, 48, 0);

    // 5) dtT[d] = softplus(dbc[:,0:16] @ dt_w[d]^T + dt_b[d])^T -> xzT rows 0:512
    for (int d = 0; d < 2; ++d)
        gemm_bf16<1, 0, 0, 1><<<dim3(8, 128), blk, 0, stream>>>(
            dbc + (size_t)d * 8192 * 48, dt_w + (size_t)d * 512 * 16,
            dt_b + (size_t)d * 512,
            xzT + (size_t)d * 1024 * 8192,
            8192, 512, 16, 48, 16, 8192, 0);

    // 6) single-pass chunked scan + gated mean-pool accumulation
    scan_kernel<<<dim3(1024), blk, 0, stream>>>(xzT, uT, dbc, A_log, Dp, gsum);

    // 7) projections to output
    final_kernel<<<dim3(4), blk, 0, stream>>>(gsum, out_w, op_w, op_b, out);
}

// Round 7
// 334.153 us; speedup vs baseline: 2.7349x; 1.0661x over previous
//
#include <hip/hip_runtime.h>
#include <stdint.h>

// MambaEncoder on MI355X (gfx950).
// ALL inputs and the output are FLOAT32. Intermediates bf16 in workspace,
// TIME-MAJOR (transposed: [ch][t]) so the scan/conv read contiguous vectors.
// GEMMs: bf16 MFMA, fp32 accum, dirs folded into grid.z. Scan: single-pass
// chunked associative scan with LDS-staged B/C (shared across the 4 waves).
// Shapes: B=4, L=2048, d_model=512, hidden=256, d_inner=512, N=16, dt_rank=16, 2 dirs.

typedef unsigned short u16;
typedef __bf16 bf16x8 __attribute__((ext_vector_type(8)));
typedef float f32x4 __attribute__((ext_vector_type(4)));

__device__ __forceinline__ float b2f(u16 h) {
    union { unsigned int u; float f; } c; c.u = ((unsigned int)h) << 16; return c.f;
}
__device__ __forceinline__ u16 f2b(float f) {   // round-to-nearest-even
    union { float f; unsigned int u; } c; c.f = f;
    unsigned int r = c.u + 0x7FFFu + ((c.u >> 16) & 1u);
    return (u16)(r >> 16);
}
// unpack packed pair of bf16 (lo,hi) from one u32 word
__device__ __forceinline__ void unpk2(unsigned int u, float& lo, float& hi) {
    union { unsigned int x; float f; } c0, c1;
    c0.x = u << 16; c1.x = u & 0xffff0000u;
    lo = c0.f; hi = c1.f;
}

// ---------------------------------------------------------------------------
// bf16-MFMA GEMM: C = act(A @ W^T + bias), A[M,K], W[N,K] fp32, BM=BN=64, BK=32.
// AF32:   A is fp32 global input (else bf16 u16 intermediate).
// ATRANS: A stored transposed [K][M] with row length lda (K%32==0, no flip).
// CTRANS: store C transposed: CT[n][m], row length ldc (N%64==0).
// ZFLIP:  flip = blockIdx.z (A row (b,l)->(b,2047-l), L=2048).
// z-strides (elements) select the direction slice for A/W/bias/C.
// ---------------------------------------------------------------------------
template<int ACT, int AF32, int ATRANS, int CTRANS, int ZFLIP>
__global__ __launch_bounds__(256)
void gemm_bf16(const void* __restrict__ Av, const float* __restrict__ W,
               const float* __restrict__ bias, u16* __restrict__ C,
               int M, int N, int K, int lda, int ldw, int ldc,
               size_t azs, size_t wzs, size_t czs, int bzs)
{
    __shared__ u16 As[64 * 40];   // [m][k], pad 40: 2-way bank alias (free)
    __shared__ u16 Ws[64 * 40];   // [n][k]
    const int z    = blockIdx.z;
    const int flip = ZFLIP ? z : 0;
    W += (size_t)z * wzs;
    C += (size_t)z * czs;
    if (bias) bias += (size_t)z * bzs;
    const u16*   A16 = (const u16*)Av + (AF32 ? 0 : (size_t)z * azs);
    const float* A32 = (const float*)Av + (AF32 ? (size_t)z * azs : 0);

    const int tid  = threadIdx.x;
    const int n0   = blockIdx.x * 64;
    const int m0   = blockIdx.y * 64;
    const int r    = tid >> 2;      // staging row 0..63
    const int seg  = tid & 3;       // 8-elem segment 0..3
    const int w    = tid >> 6;      // wave 0..3
    const int lane = tid & 63;
    const int r16  = lane & 15;
    const int q    = lane >> 4;     // quad 0..3

    f32x4 acc[4];
    #pragma unroll
    for (int i = 0; i < 4; ++i) acc[i] = (f32x4){0.f, 0.f, 0.f, 0.f};

    const int KT = (K + 31) >> 5;
    for (int kt = 0; kt < KT; ++kt) {
        const int kk = (kt << 5) + seg * 8;
        // --- stage A tile As[m][k] ---
        if (ATRANS) {
            // A is [K][M]: thread reads 8 m-values of one k-row, scatters to As.
            int k  = tid >> 3;          // 0..31
            int sg = tid & 7;           // 0..7
            const u16* sp = A16 + (size_t)((kt << 5) + k) * lda + m0 + sg * 8;
            uint4 v = *(const uint4*)sp;
            const u16* vs = (const u16*)&v;
            #pragma unroll
            for (int e = 0; e < 8; ++e) As[(sg * 8 + e) * 40 + k] = vs[e];
        } else {
            int m   = m0 + r;           // M % 64 == 0: always valid
            int src = flip ? ((m & ~2047) | (2047 - (m & 2047))) : m;
            union { u16 s[8]; uint4 v; } t;
            if (AF32) {
                const float* sp = A32 + (size_t)src * lda;
                if (kk + 8 <= K) {
                    float4 f0 = *(const float4*)(sp + kk);
                    float4 f1 = *(const float4*)(sp + kk + 4);
                    t.s[0] = f2b(f0.x); t.s[1] = f2b(f0.y);
                    t.s[2] = f2b(f0.z); t.s[3] = f2b(f0.w);
                    t.s[4] = f2b(f1.x); t.s[5] = f2b(f1.y);
                    t.s[6] = f2b(f1.z); t.s[7] = f2b(f1.w);
                } else {
                    #pragma unroll
                    for (int e = 0; e < 8; ++e)
                        t.s[e] = ((kk + e) < K) ? f2b(sp[kk + e]) : (u16)0;
                }
            } else {
                const u16* sp = A16 + (size_t)src * lda;
                if (kk + 8 <= K) {
                    t.v = *(const uint4*)(sp + kk);
                } else {
                    #pragma unroll
                    for (int e = 0; e < 8; ++e)
                        t.s[e] = ((kk + e) < K) ? sp[kk + e] : (u16)0;
                }
            }
            *(uint4*)(&As[r * 40 + seg * 8]) = t.v;
        }
        // --- stage W row n (fp32 -> bf16) ---
        {
            int n = n0 + r;
            const float* sp = W + (size_t)n * ldw;
            union { u16 s[8]; uint4 v; } t;
            if (n < N && kk + 8 <= K) {
                float4 f0 = *(const float4*)(sp + kk);
                float4 f1 = *(const float4*)(sp + kk + 4);
                t.s[0] = f2b(f0.x); t.s[1] = f2b(f0.y);
                t.s[2] = f2b(f0.z); t.s[3] = f2b(f0.w);
                t.s[4] = f2b(f1.x); t.s[5] = f2b(f1.y);
                t.s[6] = f2b(f1.z); t.s[7] = f2b(f1.w);
            } else {
                #pragma unroll
                for (int e = 0; e < 8; ++e)
                    t.s[e] = (n < N && (kk + e) < K) ? f2b(sp[kk + e]) : (u16)0;
            }
            *(uint4*)(&Ws[r * 40 + seg * 8]) = t.v;
        }
        __syncthreads();
        // A-frag: A[m=lane&15][k=quad*8+j]; B-frag: B[k][n=lane&15] = W[n][k]
        bf16x8 af = *(const bf16x8*)(&As[(w * 16 + r16) * 40 + q * 8]);
        #pragma unroll
        for (int nt = 0; nt < 4; ++nt) {
            bf16x8 wf = *(const bf16x8*)(&Ws[(nt * 16 + r16) * 40 + q * 8]);
            acc[nt] = __builtin_amdgcn_mfma_f32_16x16x32_bf16(af, wf, acc[nt], 0, 0, 0);
        }
        __syncthreads();
    }
    // epilogue: D[row=q*4+rg (m), col=r16 (n)]
    #pragma unroll
    for (int nt = 0; nt < 4; ++nt) {
        int n = n0 + nt * 16 + r16;
        if (n >= N) continue;
        float bv = bias ? bias[n] : 0.f;
        if (CTRANS) {
            union { u16 s[4]; uint2 v; } pk;
            #pragma unroll
            for (int rg = 0; rg < 4; ++rg) {
                float v = acc[nt][rg] + bv;
                if (ACT == 1) v = (v > 20.f) ? v : __logf(1.f + __expf(v));
                pk.s[rg] = f2b(v);
            }
            *(uint2*)(C + (size_t)n * ldc + m0 + w * 16 + q * 4) = pk.v;
        } else {
            #pragma unroll
            for (int rg = 0; rg < 4; ++rg) {
                int m = m0 + w * 16 + q * 4 + rg;
                float v = acc[nt][rg] + bv;
                if (ACT == 1) v = (v > 20.f) ? v : __logf(1.f + __expf(v));
                C[(size_t)m * ldc + n] = f2b(v);
            }
        }
    }
}

// ---------------------------------------------------------------------------
// Depthwise causal conv (4 taps) + silu, time-major.
// xzT [2][1024][8192]: xi rows 0:512 per dir. uT [2][512][8192].
// Thread: (d, ch, b, tile) — 32 outputs along t from a 40-value window.
// ---------------------------------------------------------------------------
__global__ __launch_bounds__(256)
void conv_silu_T(const u16* __restrict__ xzT, const float* __restrict__ cw,
                 const float* __restrict__ cb, u16* __restrict__ uT)
{
    int g    = blockIdx.x * 256 + threadIdx.x;
    int tile = g & 63;
    int b    = (g >> 6) & 3;
    int ch   = (g >> 8) & 511;
    int d    = g >> 17;
    int l0   = tile * 32;
    const u16* row = xzT + ((size_t)d * 1024 + ch) * 8192 + b * 2048;

    union { u16 s[40]; uint4 v[5]; } wd;
    wd.v[0] = (tile > 0) ? *(const uint4*)(row + l0 - 8) : (uint4){0, 0, 0, 0};
    #pragma unroll
    for (int i = 0; i < 4; ++i) wd.v[1 + i] = *(const uint4*)(row + l0 + i * 8);

    const float* wp = cw + (size_t)(d * 512 + ch) * 4;
    float c0 = wp[0], c1 = wp[1], c2 = wp[2], c3 = wp[3];
    float bias = cb[d * 512 + ch];

    union { u16 s[32]; uint4 v[4]; } o;
    #pragma unroll
    for (int i = 0; i < 32; ++i) {
        float acc = bias + c0 * b2f(wd.s[5 + i]) + c1 * b2f(wd.s[6 + i])
                         + c2 * b2f(wd.s[7 + i]) + c3 * b2f(wd.s[8 + i]);
        o.s[i] = f2b(acc / (1.f + __expf(-acc)));
    }
    u16* orow = uT + ((size_t)d * 512 + ch) * 8192 + b * 2048 + l0;
    #pragma unroll
    for (int i = 0; i < 4; ++i) ((uint4*)orow)[i] = o.v[i];
}

// ---------------------------------------------------------------------------
// Single-pass chunked associative scan with LDS-staged B/C.
// Block = 4 waves = 4 channels of one (d,b); wave lane = chunk (64 x 32 steps).
// B/C rows are IDENTICAL across the 4 waves -> stage each 8-step tile into
// LDS once per block (32 KB), read via ds_read_b64 (72 B slots: 8 B aligned,
// lane-stride 144 dw = 16 mod 32 -> 2-way alias, free per m136).
// Gated mean-pool decomposes linearly in chunk-start state h0:
//   sum_t g_t*(C_t.h_t + u_t*D) = alpha + beta . h0
// One data pass accumulates (P,S,alpha,beta); wave prefix gives h0.
// NOTE: no min-waves clamp (R4: (256,4) forced VGPR=64 -> 1.7 GB spill).
// ---------------------------------------------------------------------------
__global__ __launch_bounds__(256)
void scan_kernel(const u16* __restrict__ xzT, const u16* __restrict__ uT,
                 const u16* __restrict__ dbc, const float* __restrict__ A_log,
                 const float* __restrict__ Dp, float* __restrict__ gsum)
{
    __shared__ char bc[512 * 72];             // 36,864 B: [idx][B:32|C:32|pad:8]
    const int tid  = threadIdx.x;
    const int wv   = tid >> 6;
    const int lane = tid & 63;                // chunk index
    const int blk  = blockIdx.x;              // 0..1023
    const int bd   = blk >> 7;                // d*4+b
    const int d    = bd >> 2, b = bd & 3;
    const int ch   = (blk & 127) * 4 + wv;

    const u16* pdt = xzT + ((size_t)d * 1024 + ch) * 8192 + b * 2048 + lane * 32;
    const u16* pz  = xzT + ((size_t)d * 1024 + 512 + ch) * 8192 + b * 2048 + lane * 32;
    const u16* pu  = uT + ((size_t)d * 512 + ch) * 8192 + b * 2048 + lane * 32;
    const u16* pBCbase = dbc + ((size_t)d * 8192 + b * 2048) * 48;

    float a[16];
    #pragma unroll
    for (int n = 0; n < 16; ++n) a[n] = -__expf(A_log[(d * 512 + ch) * 16 + n]);
    const float Dv = Dp[d * 512 + ch];

    float P[16], S[16], beta[16];
    #pragma unroll
    for (int n = 0; n < 16; ++n) { P[n] = 1.f; S[n] = 0.f; beta[n] = 0.f; }
    float alpha = 0.f;

    for (int gq = 0; gq < 4; ++gq) {
        // ---- cooperative stage of this tile's B/C rows (idx = lane*8+s) ----
        __syncthreads();                       // prior tile fully consumed
        #pragma unroll
        for (int rr = 0; rr < 2; ++rr) {
            int idx = tid * 2 + rr;
            int t   = ((idx >> 3) << 5) + (gq << 3) + (idx & 7);
            const uint4* src = (const uint4*)(pBCbase + (size_t)t * 48 + 16);
            uint4 v0 = src[0], v1 = src[1], v2 = src[2], v3 = src[3];
            char* dst = &bc[idx * 72];
            *(uint2*)(dst +  0) = (uint2){v0.x, v0.y};
            *(uint2*)(dst +  8) = (uint2){v0.z, v0.w};
            *(uint2*)(dst + 16) = (uint2){v1.x, v1.y};
            *(uint2*)(dst + 24) = (uint2){v1.z, v1.w};
            *(uint2*)(dst + 32) = (uint2){v2.x, v2.y};
            *(uint2*)(dst + 40) = (uint2){v2.z, v2.w};
            *(uint2*)(dst + 48) = (uint2){v3.x, v3.y};
            *(uint2*)(dst + 56) = (uint2){v3.z, v3.w};
        }
        __syncthreads();

        uint4 vdt = *(const uint4*)(pdt + gq * 8);
        uint4 vu  = *(const uint4*)(pu + gq * 8);
        uint4 vz  = *(const uint4*)(pz + gq * 8);
        const u16* ds = (const u16*)&vdt;
        const u16* us = (const u16*)&vu;
        const u16* zs = (const u16*)&vz;

        #pragma unroll
        for (int s = 0; s < 8; ++s) {
            float dt = b2f(ds[s]), uv = b2f(us[s]), zv = b2f(zs[s]);
            const char* rowp = &bc[(lane * 8 + s) * 72];
            uint2 q0 = *(const uint2*)(rowp +  0);   // B n=0..3
            uint2 q1 = *(const uint2*)(rowp +  8);   // B n=4..7
            uint2 q2 = *(const uint2*)(rowp + 16);   // B n=8..11
            uint2 q3 = *(const uint2*)(rowp + 24);   // B n=12..15
            uint2 q4 = *(const uint2*)(rowp + 32);   // C n=0..3
            uint2 q5 = *(const uint2*)(rowp + 40);   // C n=4..7
            uint2 q6 = *(const uint2*)(rowp + 48);   // C n=8..11
            uint2 q7 = *(const uint2*)(rowp + 56);   // C n=12..15
            unsigned int Bw[8] = {q0.x, q0.y, q1.x, q1.y, q2.x, q2.y, q3.x, q3.y};
            unsigned int Cw[8] = {q4.x, q4.y, q5.x, q5.y, q6.x, q6.y, q7.x, q7.y};

            float du = dt * uv;
            float g  = zv / (1.f + __expf(-zv));   // silu(z)
            float dotCS = 0.f;
            #pragma unroll
            for (int j = 0; j < 8; ++j) {
                float B0, B1, C0, C1;
                unpk2(Bw[j], B0, B1);
                unpk2(Cw[j], C0, C1);
                int n0i = 2 * j, n1i = 2 * j + 1;
                float dA0 = __expf(dt * a[n0i]);
                float dA1 = __expf(dt * a[n1i]);
                S[n0i] = fmaf(dA0, S[n0i], du * B0);
                S[n1i] = fmaf(dA1, S[n1i], du * B1);
                P[n0i] *= dA0;
                P[n1i] *= dA1;
                dotCS = fmaf(C0, S[n0i], dotCS);
                dotCS = fmaf(C1, S[n1i], dotCS);
                beta[n0i] = fmaf(g * C0, P[n0i], beta[n0i]);
                beta[n1i] = fmaf(g * C1, P[n1i], beta[n1i]);
            }
            alpha = fmaf(g, fmaf(uv, Dv, dotCS), alpha);
        }
    }
    // ---- wave inclusive prefix on (P,S) ----
    #pragma unroll
    for (int off = 1; off < 64; off <<= 1) {
        #pragma unroll
        for (int n = 0; n < 16; ++n) {
            float Pp = __shfl_up(P[n], off);
            float Sp = __shfl_up(S[n], off);
            Pp = (lane >= off) ? Pp : 1.f;
            Sp = (lane >= off) ? Sp : 0.f;
            S[n] = fmaf(P[n], Sp, S[n]);
            P[n] *= Pp;
        }
    }
    // ---- epilogue: gacc = alpha + beta . h0 (h0 = exclusive prefix) ----
    float gacc = alpha;
    #pragma unroll
    for (int n = 0; n < 16; ++n) {
        float Hs = __shfl_up(S[n], 1);
        float h0 = (lane == 0) ? 0.f : Hs;
        gacc = fmaf(beta[n], h0, gacc);
    }
    #pragma unroll
    for (int off = 1; off < 64; off <<= 1) gacc += __shfl_xor(gacc, off);
    if (lane == 0) gsum[bd * 512 + ch] = gacc;
}

// ---------------------------------------------------------------------------
// Epilogue: gbar = gsum/L; embd[512] = concat_d(gbar[d] @ out_w[d]^T);
// out[b,i] = embd @ op_w[i,:]^T + op_b[i]  (all fp32). One block per batch b.
// ---------------------------------------------------------------------------
__global__ __launch_bounds__(256)
void final_kernel(const float* __restrict__ gsum, const float* __restrict__ out_w,
                  const float* __restrict__ op_w, const float* __restrict__ op_b,
                  float* __restrict__ out)
{
    __shared__ float gs[1024];
    __shared__ float embd[512];
    int b = blockIdx.x, tid = threadIdx.x;
    for (int i = tid; i < 1024; i += 256) {
        int dd = i >> 9, c = i & 511;
        gs[i] = gsum[(dd * 4 + b) * 512 + c];
    }
    __syncthreads();
    for (int j = tid; j < 512; j += 256) {
        int dd = j >> 8, jj = j & 255;
        const float* wp = out_w + (size_t)(dd * 256 + jj) * 512;
        const float* gp = gs + dd * 512;
        float s = 0.f;
        for (int c = 0; c < 512; ++c) s = fmaf(gp[c], wp[c], s);
        embd[j] = s * (1.0f / 2048.0f);
    }
    __syncthreads();
    {
        int i = tid;
        float s = op_b[i];
        const float* wp = op_w + (size_t)i * 512;
        for (int j = 0; j < 512; ++j) s = fmaf(embd[j], wp[j], s);
        out[b * 256 + i] = s;
    }
}

// ---------------------------------------------------------------------------
extern "C" void kernel_launch(void* const* d_in, const int* in_sizes, int n_in,
                              void* d_out, int out_size, void* d_ws, size_t ws_size,
                              hipStream_t stream)
{
    (void)in_sizes; (void)n_in; (void)out_size; (void)ws_size;
    const float* x       = (const float*)d_in[0];   // [4,2048,512]
    const float* ip_w    = (const float*)d_in[1];   // [256,512]
    const float* ip_b    = (const float*)d_in[2];   // [256]
    const float* in_w    = (const float*)d_in[3];   // [2,1024,256]
    const float* conv_w  = (const float*)d_in[4];   // [2,512,4]
    const float* conv_b  = (const float*)d_in[5];   // [2,512]
    const float* xproj_w = (const float*)d_in[6];   // [2,48,512]
    const float* dt_w    = (const float*)d_in[7];   // [2,512,16]
    const float* dt_b    = (const float*)d_in[8];   // [2,512]
    const float* A_log   = (const float*)d_in[9];   // [2,512,16]
    const float* Dp      = (const float*)d_in[10];  // [2,512]
    const float* out_w   = (const float*)d_in[11];  // [2,256,512]
    const float* op_w    = (const float*)d_in[12];  // [256,512]
    const float* op_b    = (const float*)d_in[13];  // [256]
    float* out = (float*)d_out;                     // [4,256]

    // Workspace (51,920,896 B):
    //   xzT  [0,        33554432)  [2][1024][8192] bf16, time-major; rows 0:512
    //                              = xi (later overwritten by dtT), 512:1024 = z
    //   uT   [33554432, 50331648)  [2][512][8192]  bf16, time-major (step 3)
    //   hbuf [33554432, 37748736)  [8192][256]     bf16 row-major (ALIAS in uT;
    //                              dead after step 2, before uT is written)
    //   dbc  [50331648, 51904512)  [2][8192][48]   bf16 row-major
    //   gsum [51904512, 51920896)  [8][512]        fp32
    char* ws = (char*)d_ws;
    u16*   xzT  = (u16*)(ws + 0);
    u16*   uT   = (u16*)(ws + 33554432);
    u16*   hbuf = (u16*)(ws + 33554432);
    u16*   dbc  = (u16*)(ws + 50331648);
    float* gsum = (float*)(ws + 51904512);

    dim3 blk(256);

    // 1) in_proj: hbuf = x @ ip_w^T + ip_b   [8192,256] row-major
    gemm_bf16<0, 1, 0, 0, 0><<<dim3(4, 128, 1), blk, 0, stream>>>(
        x, ip_w, ip_b, hbuf, 8192, 256, 512, 512, 512, 256, 0, 0, 0, 0);

    // 2) xzT[d] = (hbuf(_flip d) @ in_w[d]^T)^T   [1024][8192], grid.z = dir
    gemm_bf16<0, 0, 0, 1, 1><<<dim3(16, 128, 2), blk, 0, stream>>>(
        hbuf, in_w, nullptr, xzT, 8192, 1024, 256, 256, 256, 8192,
        0, (size_t)1024 * 256, (size_t)1024 * 8192, 0);

    // 3) uT = silu(causal_conv(xiT) + cb)   (hbuf region now dead)
    conv_silu_T<<<dim3(1024), blk, 0, stream>>>(xzT, conv_w, conv_b, uT);

    // 4) dbc[d] = (uT[d])^T @ xproj_w[d]^T   [8192,48], A transposed, grid.z = dir
    gemm_bf16<0, 0, 1, 0, 0><<<dim3(1, 128, 2), blk, 0, stream>>>(
        uT, xproj_w, nullptr, dbc, 8192, 48, 512, 8192, 512, 48,
        (size_t)512 * 8192, (size_t)48 * 512, (size_t)8192 * 48, 0);

    // 5) dtT[d] = softplus(dbc[:,0:16] @ dt_w[d]^T + dt_b[d])^T -> xzT rows 0:512
    gemm_bf16<1, 0, 0, 1, 0><<<dim3(8, 128, 2), blk, 0, stream>>>(
        dbc, dt_w, dt_b, xzT, 8192, 512, 16, 48, 16, 8192,
        (size_t)8192 * 48, (size_t)512 * 16, (size_t)1024 * 8192, 512);

    // 6) single-pass chunked scan (LDS-staged B/C) + gated mean-pool
    scan_kernel<<<dim3(1024), blk, 0, stream>>>(xzT, uT, dbc, A_log, Dp, gsum);

    // 7) projections to output
    final_kernel<<<dim3(4), blk, 0, stream>>>(gsum, out_w, op_w, op_b, out);
}

// Round 8
// 297.842 us; speedup vs baseline: 3.0684x; 1.1219x over previous
//
#include <hip/hip_runtime.h>
#include <stdint.h>

// MambaEncoder on MI355X (gfx950).
// ALL inputs and the output are FLOAT32. Intermediates bf16 in workspace,
// TIME-MAJOR so the scan/conv read contiguous vectors. dbc is stored n-major
// (dbcT[2][48][8192]) so scan B/C loads are coalesced uint4 — no LDS staging
// (R7: LDS staging caused 16-way bank conflicts + VGPR 208).
// Scan: single-pass chunked associative scan, 8 states/thread (n split across
// wave pairs) to cut register pressure.
// Shapes: B=4, L=2048, d_model=512, hidden=256, d_inner=512, N=16, dt_rank=16, 2 dirs.

typedef unsigned short u16;
typedef __bf16 bf16x8 __attribute__((ext_vector_type(8)));
typedef float f32x4 __attribute__((ext_vector_type(4)));

__device__ __forceinline__ float b2f(u16 h) {
    union { unsigned int u; float f; } c; c.u = ((unsigned int)h) << 16; return c.f;
}
__device__ __forceinline__ u16 f2b(float f) {   // round-to-nearest-even
    union { float f; unsigned int u; } c; c.f = f;
    unsigned int r = c.u + 0x7FFFu + ((c.u >> 16) & 1u);
    return (u16)(r >> 16);
}
// unpack packed pair of bf16 (lo,hi) from one u32 word
__device__ __forceinline__ void unpk2(unsigned int u, float& lo, float& hi) {
    union { unsigned int x; float f; } c0, c1;
    c0.x = u << 16; c1.x = u & 0xffff0000u;
    lo = c0.f; hi = c1.f;
}

// ---------------------------------------------------------------------------
// bf16-MFMA GEMM: C = act(A @ W^T + bias), A[M,K], W[N,K] fp32, BM=BN=64, BK=32.
// AF32:   A is fp32 global input (else bf16 u16 intermediate).
// ATRANS: A stored transposed [K][M] with row length lda (rows >= K read as 0).
// CTRANS: store C transposed: CT[n][m], row length ldc.
// ZFLIP:  flip = blockIdx.z (A row (b,l)->(b,2047-l), L=2048).
// z-strides (elements) select the direction slice for A/W/bias/C.
// ---------------------------------------------------------------------------
template<int ACT, int AF32, int ATRANS, int CTRANS, int ZFLIP>
__global__ __launch_bounds__(256)
void gemm_bf16(const void* __restrict__ Av, const float* __restrict__ W,
               const float* __restrict__ bias, u16* __restrict__ C,
               int M, int N, int K, int lda, int ldw, int ldc,
               size_t azs, size_t wzs, size_t czs, int bzs)
{
    __shared__ u16 As[64 * 40];   // [m][k], pad 40: 2-way bank alias (free)
    __shared__ u16 Ws[64 * 40];   // [n][k]
    const int z    = blockIdx.z;
    const int flip = ZFLIP ? z : 0;
    W += (size_t)z * wzs;
    C += (size_t)z * czs;
    if (bias) bias += (size_t)z * bzs;
    const u16*   A16 = (const u16*)Av + (AF32 ? 0 : (size_t)z * azs);
    const float* A32 = (const float*)Av + (AF32 ? (size_t)z * azs : 0);

    const int tid  = threadIdx.x;
    const int n0   = blockIdx.x * 64;
    const int m0   = blockIdx.y * 64;
    const int r    = tid >> 2;      // staging row 0..63
    const int seg  = tid & 3;       // 8-elem segment 0..3
    const int w    = tid >> 6;      // wave 0..3
    const int lane = tid & 63;
    const int r16  = lane & 15;
    const int q    = lane >> 4;     // quad 0..3

    f32x4 acc[4];
    #pragma unroll
    for (int i = 0; i < 4; ++i) acc[i] = (f32x4){0.f, 0.f, 0.f, 0.f};

    const int KT = (K + 31) >> 5;
    for (int kt = 0; kt < KT; ++kt) {
        const int kk = (kt << 5) + seg * 8;
        // --- stage A tile As[m][k] ---
        if (ATRANS) {
            // A is [K][M]: thread reads 8 m-values of one k-row, scatters to As.
            int k  = tid >> 3;          // 0..31
            int sg = tid & 7;           // 0..7
            int kd = (kt << 5) + k;
            uint4 v = (uint4){0, 0, 0, 0};
            if (kd < K) v = *(const uint4*)(A16 + (size_t)kd * lda + m0 + sg * 8);
            const u16* vs = (const u16*)&v;
            #pragma unroll
            for (int e = 0; e < 8; ++e) As[(sg * 8 + e) * 40 + k] = vs[e];
        } else {
            int m   = m0 + r;           // M % 64 == 0: always valid
            int src = flip ? ((m & ~2047) | (2047 - (m & 2047))) : m;
            union { u16 s[8]; uint4 v; } t;
            if (AF32) {
                const float* sp = A32 + (size_t)src * lda;
                if (kk + 8 <= K) {
                    float4 f0 = *(const float4*)(sp + kk);
                    float4 f1 = *(const float4*)(sp + kk + 4);
                    t.s[0] = f2b(f0.x); t.s[1] = f2b(f0.y);
                    t.s[2] = f2b(f0.z); t.s[3] = f2b(f0.w);
                    t.s[4] = f2b(f1.x); t.s[5] = f2b(f1.y);
                    t.s[6] = f2b(f1.z); t.s[7] = f2b(f1.w);
                } else {
                    #pragma unroll
                    for (int e = 0; e < 8; ++e)
                        t.s[e] = ((kk + e) < K) ? f2b(sp[kk + e]) : (u16)0;
                }
            } else {
                const u16* sp = A16 + (size_t)src * lda;
                if (kk + 8 <= K) {
                    t.v = *(const uint4*)(sp + kk);
                } else {
                    #pragma unroll
                    for (int e = 0; e < 8; ++e)
                        t.s[e] = ((kk + e) < K) ? sp[kk + e] : (u16)0;
                }
            }
            *(uint4*)(&As[r * 40 + seg * 8]) = t.v;
        }
        // --- stage W row n (fp32 -> bf16) ---
        {
            int n = n0 + r;
            const float* sp = W + (size_t)n * ldw;
            union { u16 s[8]; uint4 v; } t;
            if (n < N && kk + 8 <= K) {
                float4 f0 = *(const float4*)(sp + kk);
                float4 f1 = *(const float4*)(sp + kk + 4);
                t.s[0] = f2b(f0.x); t.s[1] = f2b(f0.y);
                t.s[2] = f2b(f0.z); t.s[3] = f2b(f0.w);
                t.s[4] = f2b(f1.x); t.s[5] = f2b(f1.y);
                t.s[6] = f2b(f1.z); t.s[7] = f2b(f1.w);
            } else {
                #pragma unroll
                for (int e = 0; e < 8; ++e)
                    t.s[e] = (n < N && (kk + e) < K) ? f2b(sp[kk + e]) : (u16)0;
            }
            *(uint4*)(&Ws[r * 40 + seg * 8]) = t.v;
        }
        __syncthreads();
        // A-frag: A[m=lane&15][k=quad*8+j]; B-frag: B[k][n=lane&15] = W[n][k]
        bf16x8 af = *(const bf16x8*)(&As[(w * 16 + r16) * 40 + q * 8]);
        #pragma unroll
        for (int nt = 0; nt < 4; ++nt) {
            bf16x8 wf = *(const bf16x8*)(&Ws[(nt * 16 + r16) * 40 + q * 8]);
            acc[nt] = __builtin_amdgcn_mfma_f32_16x16x32_bf16(af, wf, acc[nt], 0, 0, 0);
        }
        __syncthreads();
    }
    // epilogue: D[row=q*4+rg (m), col=r16 (n)]
    #pragma unroll
    for (int nt = 0; nt < 4; ++nt) {
        int n = n0 + nt * 16 + r16;
        if (n >= N) continue;
        float bv = bias ? bias[n] : 0.f;
        if (CTRANS) {
            union { u16 s[4]; uint2 v; } pk;
            #pragma unroll
            for (int rg = 0; rg < 4; ++rg) {
                float v = acc[nt][rg] + bv;
                if (ACT == 1) v = (v > 20.f) ? v : __logf(1.f + __expf(v));
                pk.s[rg] = f2b(v);
            }
            *(uint2*)(C + (size_t)n * ldc + m0 + w * 16 + q * 4) = pk.v;
        } else {
            #pragma unroll
            for (int rg = 0; rg < 4; ++rg) {
                int m = m0 + w * 16 + q * 4 + rg;
                float v = acc[nt][rg] + bv;
                if (ACT == 1) v = (v > 20.f) ? v : __logf(1.f + __expf(v));
                C[(size_t)m * ldc + n] = f2b(v);
            }
        }
    }
}

// ---------------------------------------------------------------------------
// Depthwise causal conv (4 taps) + silu, time-major.
// xzT [2][1024][8192]: xi rows 0:512 per dir. uT [2][512][8192].
// Thread: (d, ch, b, tile) — 32 outputs along t from a 40-value window.
// ---------------------------------------------------------------------------
__global__ __launch_bounds__(256)
void conv_silu_T(const u16* __restrict__ xzT, const float* __restrict__ cw,
                 const float* __restrict__ cb, u16* __restrict__ uT)
{
    int g    = blockIdx.x * 256 + threadIdx.x;
    int tile = g & 63;
    int b    = (g >> 6) & 3;
    int ch   = (g >> 8) & 511;
    int d    = g >> 17;
    int l0   = tile * 32;
    const u16* row = xzT + ((size_t)d * 1024 + ch) * 8192 + b * 2048;

    union { u16 s[40]; uint4 v[5]; } wd;
    wd.v[0] = (tile > 0) ? *(const uint4*)(row + l0 - 8) : (uint4){0, 0, 0, 0};
    #pragma unroll
    for (int i = 0; i < 4; ++i) wd.v[1 + i] = *(const uint4*)(row + l0 + i * 8);

    const float* wp = cw + (size_t)(d * 512 + ch) * 4;
    float c0 = wp[0], c1 = wp[1], c2 = wp[2], c3 = wp[3];
    float bias = cb[d * 512 + ch];

    union { u16 s[32]; uint4 v[4]; } o;
    #pragma unroll
    for (int i = 0; i < 32; ++i) {
        float acc = bias + c0 * b2f(wd.s[5 + i]) + c1 * b2f(wd.s[6 + i])
                         + c2 * b2f(wd.s[7 + i]) + c3 * b2f(wd.s[8 + i]);
        o.s[i] = f2b(acc / (1.f + __expf(-acc)));
    }
    u16* orow = uT + ((size_t)d * 512 + ch) * 8192 + b * 2048 + l0;
    #pragma unroll
    for (int i = 0; i < 4; ++i) ((uint4*)orow)[i] = o.v[i];
}

// ---------------------------------------------------------------------------
// Single-pass chunked associative scan, 8 states/thread.
// Block = 4 waves = 2 channels x 2 n-halves of one (d,b). Wave lane = chunk
// (64 chunks x 32 steps). B/C read n-major from dbcT: per (tile, n) one
// contiguous uint4 (lane stride 64 B -> coalesced). Gated mean-pool
// decomposes linearly in chunk-start state h0: gacc = alpha + beta . h0;
// the two n-halves' partials are combined via 4-float LDS.
// NOTE: no min-waves clamp (R4: (256,4) forced VGPR=64 -> 1.7 GB spill).
// ---------------------------------------------------------------------------
__global__ __launch_bounds__(256)
void scan_kernel(const u16* __restrict__ xzT, const u16* __restrict__ uT,
                 const u16* __restrict__ dbcT, const float* __restrict__ A_log,
                 const float* __restrict__ Dp, float* __restrict__ gsum)
{
    __shared__ float part[4];
    const int tid  = threadIdx.x;
    const int wv   = tid >> 6;
    const int lane = tid & 63;                // chunk index
    const int blk  = blockIdx.x;              // 0..2047
    const int bd   = blk >> 8;                // d*4+b
    const int d    = bd >> 2, b = bd & 3;
    const int ch   = (blk & 255) * 2 + (wv >> 1);
    const int nh   = (wv & 1) * 8;            // n-half offset

    const u16* pdt = xzT + ((size_t)d * 1024 + ch) * 8192 + b * 2048 + lane * 32;
    const u16* pz  = xzT + ((size_t)d * 1024 + 512 + ch) * 8192 + b * 2048 + lane * 32;
    const u16* pu  = uT + ((size_t)d * 512 + ch) * 8192 + b * 2048 + lane * 32;
    // dbcT rows: [0:16) dt_in, [16:32) B, [32:48) C
    const u16* pB  = dbcT + ((size_t)d * 48 + 16 + nh) * 8192 + b * 2048 + lane * 32;
    const u16* pC  = dbcT + ((size_t)d * 48 + 32 + nh) * 8192 + b * 2048 + lane * 32;

    float a[8];
    #pragma unroll
    for (int n = 0; n < 8; ++n)
        a[n] = -__expf(A_log[(d * 512 + ch) * 16 + nh + n]);
    const float DvEff = (wv & 1) ? 0.f : Dp[d * 512 + ch];   // D-term once per ch

    float P[8], S[8], beta[8];
    #pragma unroll
    for (int n = 0; n < 8; ++n) { P[n] = 1.f; S[n] = 0.f; beta[n] = 0.f; }
    float alpha = 0.f;

    #pragma unroll 1
    for (int gq = 0; gq < 4; ++gq) {
        uint4 vdt = *(const uint4*)(pdt + gq * 8);
        uint4 vu  = *(const uint4*)(pu + gq * 8);
        uint4 vz  = *(const uint4*)(pz + gq * 8);
        const u16* ds = (const u16*)&vdt;
        const u16* us = (const u16*)&vu;
        const u16* zs = (const u16*)&vz;
        float dtv[8], duv[8], gv[8];
        #pragma unroll
        for (int s = 0; s < 8; ++s) {
            float dt = b2f(ds[s]), uv = b2f(us[s]), zv = b2f(zs[s]);
            dtv[s] = dt;
            duv[s] = dt * uv;
            float g = zv / (1.f + __expf(-zv));   // silu(z)
            gv[s] = g;
            alpha = fmaf(g * uv, DvEff, alpha);
        }
        #pragma unroll
        for (int n = 0; n < 8; ++n) {
            uint4 Bq = *(const uint4*)(pB + (size_t)n * 8192 + gq * 8);
            uint4 Cq = *(const uint4*)(pC + (size_t)n * 8192 + gq * 8);
            unsigned int bw[4] = {Bq.x, Bq.y, Bq.z, Bq.w};
            unsigned int cw2[4] = {Cq.x, Cq.y, Cq.z, Cq.w};
            float tp = P[n], ts = S[n], tb = beta[n], an = a[n];
            #pragma unroll
            for (int w2 = 0; w2 < 4; ++w2) {
                float B0, B1, C0, C1;
                unpk2(bw[w2], B0, B1);
                unpk2(cw2[w2], C0, C1);
                int s0 = 2 * w2, s1 = s0 + 1;
                float dA0 = __expf(dtv[s0] * an);
                ts = fmaf(dA0, ts, duv[s0] * B0);
                tp *= dA0;
                float gC0 = gv[s0] * C0;
                alpha = fmaf(gC0, ts, alpha);
                tb = fmaf(gC0, tp, tb);
                float dA1 = __expf(dtv[s1] * an);
                ts = fmaf(dA1, ts, duv[s1] * B1);
                tp *= dA1;
                float gC1 = gv[s1] * C1;
                alpha = fmaf(gC1, ts, alpha);
                tb = fmaf(gC1, tp, tb);
            }
            P[n] = tp; S[n] = ts; beta[n] = tb;
        }
    }
    // ---- wave inclusive prefix on (P,S) ----
    #pragma unroll
    for (int off = 1; off < 64; off <<= 1) {
        #pragma unroll
        for (int n = 0; n < 8; ++n) {
            float Pp = __shfl_up(P[n], off);
            float Sp = __shfl_up(S[n], off);
            Pp = (lane >= off) ? Pp : 1.f;
            Sp = (lane >= off) ? Sp : 0.f;
            S[n] = fmaf(P[n], Sp, S[n]);
            P[n] *= Pp;
        }
    }
    // ---- gacc = alpha + beta . h0 (h0 = exclusive prefix) ----
    float gacc = alpha;
    #pragma unroll
    for (int n = 0; n < 8; ++n) {
        float Hs = __shfl_up(S[n], 1);
        float h0 = (lane == 0) ? 0.f : Hs;
        gacc = fmaf(beta[n], h0, gacc);
    }
    #pragma unroll
    for (int off = 1; off < 64; off <<= 1) gacc += __shfl_xor(gacc, off);
    if (lane == 0) part[wv] = gacc;
    __syncthreads();
    if (tid < 2)
        gsum[bd * 512 + (blk & 255) * 2 + tid] = part[tid * 2] + part[tid * 2 + 1];
}

// ---------------------------------------------------------------------------
// Epilogue: gbar = gsum/L; embd[512] = concat_d(gbar[d] @ out_w[d]^T);
// out[b,i] = embd @ op_w[i,:]^T + op_b[i]  (all fp32). One block per batch b.
// ---------------------------------------------------------------------------
__global__ __launch_bounds__(256)
void final_kernel(const float* __restrict__ gsum, const float* __restrict__ out_w,
                  const float* __restrict__ op_w, const float* __restrict__ op_b,
                  float* __restrict__ out)
{
    __shared__ float gs[1024];
    __shared__ float embd[512];
    int b = blockIdx.x, tid = threadIdx.x;
    for (int i = tid; i < 1024; i += 256) {
        int dd = i >> 9, c = i & 511;
        gs[i] = gsum[(dd * 4 + b) * 512 + c];
    }
    __syncthreads();
    for (int j = tid; j < 512; j += 256) {
        int dd = j >> 8, jj = j & 255;
        const float* wp = out_w + (size_t)(dd * 256 + jj) * 512;
        const float* gp = gs + dd * 512;
        float s = 0.f;
        for (int c = 0; c < 512; ++c) s = fmaf(gp[c], wp[c], s);
        embd[j] = s * (1.0f / 2048.0f);
    }
    __syncthreads();
    {
        int i = tid;
        float s = op_b[i];
        const float* wp = op_w + (size_t)i * 512;
        for (int j = 0; j < 512; ++j) s = fmaf(embd[j], wp[j], s);
        out[b * 256 + i] = s;
    }
}

// ---------------------------------------------------------------------------
extern "C" void kernel_launch(void* const* d_in, const int* in_sizes, int n_in,
                              void* d_out, int out_size, void* d_ws, size_t ws_size,
                              hipStream_t stream)
{
    (void)in_sizes; (void)n_in; (void)out_size; (void)ws_size;
    const float* x       = (const float*)d_in[0];   // [4,2048,512]
    const float* ip_w    = (const float*)d_in[1];   // [256,512]
    const float* ip_b    = (const float*)d_in[2];   // [256]
    const float* in_w    = (const float*)d_in[3];   // [2,1024,256]
    const float* conv_w  = (const float*)d_in[4];   // [2,512,4]
    const float* conv_b  = (const float*)d_in[5];   // [2,512]
    const float* xproj_w = (const float*)d_in[6];   // [2,48,512]
    const float* dt_w    = (const float*)d_in[7];   // [2,512,16]
    const float* dt_b    = (const float*)d_in[8];   // [2,512]
    const float* A_log   = (const float*)d_in[9];   // [2,512,16]
    const float* Dp      = (const float*)d_in[10];  // [2,512]
    const float* out_w   = (const float*)d_in[11];  // [2,256,512]
    const float* op_w    = (const float*)d_in[12];  // [256,512]
    const float* op_b    = (const float*)d_in[13];  // [256]
    float* out = (float*)d_out;                     // [4,256]

    // Workspace (51,920,896 B):
    //   xzT  [0,        33554432)  [2][1024][8192] bf16, time-major; rows 0:512
    //                              = xi (later overwritten by dtT), 512:1024 = z
    //   uT   [33554432, 50331648)  [2][512][8192]  bf16, time-major (step 3)
    //   hbuf [33554432, 37748736)  [8192][256]     bf16 row-major (ALIAS in uT;
    //                              dead after step 2, before uT is written)
    //   dbcT [50331648, 51904512)  [2][48][8192]   bf16 n-major
    //   gsum [51904512, 51920896)  [8][512]        fp32
    char* ws = (char*)d_ws;
    u16*   xzT  = (u16*)(ws + 0);
    u16*   uT   = (u16*)(ws + 33554432);
    u16*   hbuf = (u16*)(ws + 33554432);
    u16*   dbcT = (u16*)(ws + 50331648);
    float* gsum = (float*)(ws + 51904512);

    dim3 blk(256);

    // 1) in_proj: hbuf = x @ ip_w^T + ip_b   [8192,256] row-major
    gemm_bf16<0, 1, 0, 0, 0><<<dim3(4, 128, 1), blk, 0, stream>>>(
        x, ip_w, ip_b, hbuf, 8192, 256, 512, 512, 512, 256, 0, 0, 0, 0);

    // 2) xzT[d] = (hbuf(_flip d) @ in_w[d]^T)^T   [1024][8192], grid.z = dir
    gemm_bf16<0, 0, 0, 1, 1><<<dim3(16, 128, 2), blk, 0, stream>>>(
        hbuf, in_w, nullptr, xzT, 8192, 1024, 256, 256, 256, 8192,
        0, (size_t)1024 * 256, (size_t)1024 * 8192, 0);

    // 3) uT = silu(causal_conv(xiT) + cb)   (hbuf region now dead)
    conv_silu_T<<<dim3(1024), blk, 0, stream>>>(xzT, conv_w, conv_b, uT);

    // 4) dbcT[d] = ((uT[d])^T @ xproj_w[d]^T)^T   [48][8192] n-major, grid.z = dir
    gemm_bf16<0, 0, 1, 1, 0><<<dim3(1, 128, 2), blk, 0, stream>>>(
        uT, xproj_w, nullptr, dbcT, 8192, 48, 512, 8192, 512, 8192,
        (size_t)512 * 8192, (size_t)48 * 512, (size_t)48 * 8192, 0);

    // 5) dtT[d] = softplus(dbcT[0:16]^T @ dt_w[d]^T + dt_b[d])^T -> xzT rows 0:512
    gemm_bf16<1, 0, 1, 1, 0><<<dim3(8, 128, 2), blk, 0, stream>>>(
        dbcT, dt_w, dt_b, xzT, 8192, 512, 16, 8192, 16, 8192,
        (size_t)48 * 8192, (size_t)512 * 16, (size_t)1024 * 8192, 512);

    // 6) single-pass chunked scan (coalesced n-major B/C) + gated mean-pool
    scan_kernel<<<dim3(2048), blk, 0, stream>>>(xzT, uT, dbcT, A_log, Dp, gsum);

    // 7) projections to output
    final_kernel<<<dim3(4), blk, 0, stream>>>(gsum, out_w, op_w, op_b, out);
}

// Round 9
// 292.526 us; speedup vs baseline: 3.1241x; 1.0182x over previous
//
#include <hip/hip_runtime.h>
#include <stdint.h>

// MambaEncoder on MI355X (gfx950).
// ALL inputs and the output are FLOAT32. Intermediates bf16 in workspace,
// TIME-MAJOR; dbc n-major (scan B/C coalesced, R8: conflicts 1.8e7 -> 0).
// Weights prepacked fp32->bf16 once per call (removes f2b from W staging).
// Steps 1-2 use a 128x128 MFMA tile (16 MFMA / 4 staging rounds); steps 4-5
// keep the 64x64 tile (skinny N/K). Scan: single-pass chunked associative
// scan, 8 states/thread, silu via v_rcp_f32.
// Shapes: B=4, L=2048, d_model=512, hidden=256, d_inner=512, N=16, dt_rank=16, 2 dirs.

typedef unsigned short u16;
typedef __bf16 bf16x8 __attribute__((ext_vector_type(8)));
typedef float f32x4 __attribute__((ext_vector_type(4)));

__device__ __forceinline__ float b2f(u16 h) {
    union { unsigned int u; float f; } c; c.u = ((unsigned int)h) << 16; return c.f;
}
__device__ __forceinline__ u16 f2b(float f) {   // round-to-nearest-even
    union { float f; unsigned int u; } c; c.f = f;
    unsigned int r = c.u + 0x7FFFu + ((c.u >> 16) & 1u);
    return (u16)(r >> 16);
}
__device__ __forceinline__ void unpk2(unsigned int u, float& lo, float& hi) {
    union { unsigned int x; float f; } c0, c1;
    c0.x = u << 16; c1.x = u & 0xffff0000u;
    lo = c0.f; hi = c1.f;
}
__device__ __forceinline__ float silu(float x) {
    return x * __builtin_amdgcn_rcpf(1.f + __expf(-x));
}

// ---------------------------------------------------------------------------
// Weight prepack: fp32 -> bf16 (RNE). Fixed segment sizes:
//   ip_w 131072 | in_w 524288 | xproj_w 49152 | dt_w 16384  (all %8==0)
// ---------------------------------------------------------------------------
__global__ __launch_bounds__(256)
void pack_weights(const float* __restrict__ s0, const float* __restrict__ s1,
                  const float* __restrict__ s2, const float* __restrict__ s3,
                  u16* __restrict__ dst)
{
    int idx = (blockIdx.x * 256 + threadIdx.x) * 8;   // 90112 threads, 720896 elems
    const float* src; int off;
    if (idx < 131072)      { src = s0; off = idx; }
    else if (idx < 655360) { src = s1; off = idx - 131072; }
    else if (idx < 704512) { src = s2; off = idx - 655360; }
    else                   { src = s3; off = idx - 704512; }
    float4 f0 = *(const float4*)(src + off);
    float4 f1 = *(const float4*)(src + off + 4);
    union { u16 s[8]; uint4 v; } t;
    t.s[0] = f2b(f0.x); t.s[1] = f2b(f0.y); t.s[2] = f2b(f0.z); t.s[3] = f2b(f0.w);
    t.s[4] = f2b(f1.x); t.s[5] = f2b(f1.y); t.s[6] = f2b(f1.z); t.s[7] = f2b(f1.w);
    *(uint4*)(dst + idx) = t.v;
}

// ---------------------------------------------------------------------------
// 128x128 MFMA GEMM (steps 1-2): C = A @ W^T + bias. M%128==0, N%128==0,
// K%32==0. W bf16 prepacked. 4 waves in 2x2; each wave 64x64 via 4x4 MFMAs.
// AF32: A fp32 (converted at staging). CTRANS: CT[n][m]. ZFLIP: dir-1 flip.
// ---------------------------------------------------------------------------
template<int AF32, int CTRANS, int ZFLIP>
__global__ __launch_bounds__(256)
void gemm128(const void* __restrict__ Av, const u16* __restrict__ Wb,
             const float* __restrict__ bias, u16* __restrict__ C,
             int M, int N, int K, int lda, int ldw, int ldc,
             size_t azs, size_t wzs, size_t czs)
{
    __shared__ u16 As[128 * 40];
    __shared__ u16 Ws[128 * 40];
    const int z    = blockIdx.z;
    const int flip = ZFLIP ? z : 0;
    Wb += (size_t)z * wzs;
    C  += (size_t)z * czs;
    const u16*   A16 = (const u16*)Av + (AF32 ? 0 : (size_t)z * azs);
    const float* A32 = (const float*)Av + (AF32 ? (size_t)z * azs : 0);

    const int tid  = threadIdx.x;
    const int n0   = blockIdx.x * 128;
    const int m0   = blockIdx.y * 128;
    const int w    = tid >> 6;
    const int lane = tid & 63;
    const int r16  = lane & 15;
    const int q    = lane >> 4;
    const int wm   = (w >> 1) * 64;   // wave row offset
    const int wn   = (w & 1) * 64;    // wave col offset

    f32x4 acc[4][4];
    #pragma unroll
    for (int i = 0; i < 4; ++i)
        #pragma unroll
        for (int j = 0; j < 4; ++j) acc[i][j] = (f32x4){0.f, 0.f, 0.f, 0.f};

    const int KT = K >> 5;
    for (int kt = 0; kt < KT; ++kt) {
        // stage A and W tiles: 2 rounds each, 256 thr x uint4
        #pragma unroll
        for (int rr = 0; rr < 2; ++rr) {
            int idx = rr * 256 + tid;
            int row = idx >> 2;            // 0..127
            int col = (kt << 5) + (idx & 3) * 8;
            {   // A
                int m   = m0 + row;
                int src = flip ? ((m & ~2047) | (2047 - (m & 2047))) : m;
                union { u16 s[8]; uint4 v; } t;
                if (AF32) {
                    const float* sp = A32 + (size_t)src * lda + col;
                    float4 f0 = *(const float4*)sp;
                    float4 f1 = *(const float4*)(sp + 4);
                    t.s[0] = f2b(f0.x); t.s[1] = f2b(f0.y);
                    t.s[2] = f2b(f0.z); t.s[3] = f2b(f0.w);
                    t.s[4] = f2b(f1.x); t.s[5] = f2b(f1.y);
                    t.s[6] = f2b(f1.z); t.s[7] = f2b(f1.w);
                } else {
                    t.v = *(const uint4*)(A16 + (size_t)src * lda + col);
                }
                *(uint4*)(&As[row * 40 + (idx & 3) * 8]) = t.v;
            }
            {   // W
                uint4 v = *(const uint4*)(Wb + (size_t)(n0 + row) * ldw + col);
                *(uint4*)(&Ws[row * 40 + (idx & 3) * 8]) = v;
            }
        }
        __syncthreads();
        bf16x8 af[4], wf[4];
        #pragma unroll
        for (int i = 0; i < 4; ++i)
            af[i] = *(const bf16x8*)(&As[(wm + i * 16 + r16) * 40 + q * 8]);
        #pragma unroll
        for (int j = 0; j < 4; ++j)
            wf[j] = *(const bf16x8*)(&Ws[(wn + j * 16 + r16) * 40 + q * 8]);
        #pragma unroll
        for (int i = 0; i < 4; ++i)
            #pragma unroll
            for (int j = 0; j < 4; ++j)
                acc[i][j] = __builtin_amdgcn_mfma_f32_16x16x32_bf16(af[i], wf[j], acc[i][j], 0, 0, 0);
        __syncthreads();
    }
    // epilogue: D[row=q*4+rg][col=r16] per 16x16 tile
    #pragma unroll
    for (int j = 0; j < 4; ++j) {
        int n = n0 + wn + j * 16 + r16;
        float bv = bias ? bias[n] : 0.f;
        #pragma unroll
        for (int i = 0; i < 4; ++i) {
            if (CTRANS) {
                union { u16 s[4]; uint2 v; } pk;
                #pragma unroll
                for (int rg = 0; rg < 4; ++rg) pk.s[rg] = f2b(acc[i][j][rg] + bv);
                *(uint2*)(C + (size_t)n * ldc + m0 + wm + i * 16 + q * 4) = pk.v;
            } else {
                #pragma unroll
                for (int rg = 0; rg < 4; ++rg) {
                    int m = m0 + wm + i * 16 + q * 4 + rg;
                    C[(size_t)m * ldc + n] = f2b(acc[i][j][rg] + bv);
                }
            }
        }
    }
}

// ---------------------------------------------------------------------------
// 64x64 MFMA GEMM (steps 4-5): skinny N/K. W bf16 prepacked. A bf16.
// ATRANS: A stored [K][M], rows >= K read as 0. CTRANS: CT[n][m].
// ACT: 0 none, 1 softplus.
// ---------------------------------------------------------------------------
template<int ACT, int ATRANS, int CTRANS>
__global__ __launch_bounds__(256)
void gemm64(const u16* __restrict__ A16, const u16* __restrict__ Wb,
            const float* __restrict__ bias, u16* __restrict__ C,
            int M, int N, int K, int lda, int ldw, int ldc,
            size_t azs, size_t wzs, size_t czs, int bzs)
{
    __shared__ u16 As[64 * 40];
    __shared__ u16 Ws[64 * 40];
    const int z = blockIdx.z;
    Wb += (size_t)z * wzs;
    C  += (size_t)z * czs;
    if (bias) bias += (size_t)z * bzs;
    const u16* A = A16 + (size_t)z * azs;

    const int tid  = threadIdx.x;
    const int n0   = blockIdx.x * 64;
    const int m0   = blockIdx.y * 64;
    const int r    = tid >> 2;
    const int seg  = tid & 3;
    const int w    = tid >> 6;
    const int lane = tid & 63;
    const int r16  = lane & 15;
    const int q    = lane >> 4;

    f32x4 acc[4];
    #pragma unroll
    for (int i = 0; i < 4; ++i) acc[i] = (f32x4){0.f, 0.f, 0.f, 0.f};

    const int KT = (K + 31) >> 5;
    for (int kt = 0; kt < KT; ++kt) {
        const int kk = (kt << 5) + seg * 8;
        if (ATRANS) {
            int k  = tid >> 3;
            int sg = tid & 7;
            int kd = (kt << 5) + k;
            uint4 v = (uint4){0, 0, 0, 0};
            if (kd < K) v = *(const uint4*)(A + (size_t)kd * lda + m0 + sg * 8);
            const u16* vs = (const u16*)&v;
            #pragma unroll
            for (int e = 0; e < 8; ++e) As[(sg * 8 + e) * 40 + k] = vs[e];
        } else {
            const u16* sp = A + (size_t)(m0 + r) * lda;
            union { u16 s[8]; uint4 v; } t;
            if (kk + 8 <= K) {
                t.v = *(const uint4*)(sp + kk);
            } else {
                #pragma unroll
                for (int e = 0; e < 8; ++e)
                    t.s[e] = ((kk + e) < K) ? sp[kk + e] : (u16)0;
            }
            *(uint4*)(&As[r * 40 + seg * 8]) = t.v;
        }
        {   // W row n (bf16)
            int n = n0 + r;
            const u16* sp = Wb + (size_t)n * ldw;
            union { u16 s[8]; uint4 v; } t;
            if (n < N && kk + 8 <= K) {
                t.v = *(const uint4*)(sp + kk);
            } else {
                #pragma unroll
                for (int e = 0; e < 8; ++e)
                    t.s[e] = (n < N && (kk + e) < K) ? sp[kk + e] : (u16)0;
            }
            *(uint4*)(&Ws[r * 40 + seg * 8]) = t.v;
        }
        __syncthreads();
        bf16x8 af = *(const bf16x8*)(&As[(w * 16 + r16) * 40 + q * 8]);
        #pragma unroll
        for (int nt = 0; nt < 4; ++nt) {
            bf16x8 wf = *(const bf16x8*)(&Ws[(nt * 16 + r16) * 40 + q * 8]);
            acc[nt] = __builtin_amdgcn_mfma_f32_16x16x32_bf16(af, wf, acc[nt], 0, 0, 0);
        }
        __syncthreads();
    }
    #pragma unroll
    for (int nt = 0; nt < 4; ++nt) {
        int n = n0 + nt * 16 + r16;
        if (n >= N) continue;
        float bv = bias ? bias[n] : 0.f;
        if (CTRANS) {
            union { u16 s[4]; uint2 v; } pk;
            #pragma unroll
            for (int rg = 0; rg < 4; ++rg) {
                float v = acc[nt][rg] + bv;
                if (ACT == 1) v = (v > 20.f) ? v : __logf(1.f + __expf(v));
                pk.s[rg] = f2b(v);
            }
            *(uint2*)(C + (size_t)n * ldc + m0 + w * 16 + q * 4) = pk.v;
        } else {
            #pragma unroll
            for (int rg = 0; rg < 4; ++rg) {
                int m = m0 + w * 16 + q * 4 + rg;
                float v = acc[nt][rg] + bv;
                if (ACT == 1) v = (v > 20.f) ? v : __logf(1.f + __expf(v));
                C[(size_t)m * ldc + n] = f2b(v);
            }
        }
    }
}

// ---------------------------------------------------------------------------
// Depthwise causal conv (4 taps) + silu, time-major.
// ---------------------------------------------------------------------------
__global__ __launch_bounds__(256)
void conv_silu_T(const u16* __restrict__ xzT, const float* __restrict__ cw,
                 const float* __restrict__ cb, u16* __restrict__ uT)
{
    int g    = blockIdx.x * 256 + threadIdx.x;
    int tile = g & 63;
    int b    = (g >> 6) & 3;
    int ch   = (g >> 8) & 511;
    int d    = g >> 17;
    int l0   = tile * 32;
    const u16* row = xzT + ((size_t)d * 1024 + ch) * 8192 + b * 2048;

    union { u16 s[40]; uint4 v[5]; } wd;
    wd.v[0] = (tile > 0) ? *(const uint4*)(row + l0 - 8) : (uint4){0, 0, 0, 0};
    #pragma unroll
    for (int i = 0; i < 4; ++i) wd.v[1 + i] = *(const uint4*)(row + l0 + i * 8);

    const float* wp = cw + (size_t)(d * 512 + ch) * 4;
    float c0 = wp[0], c1 = wp[1], c2 = wp[2], c3 = wp[3];
    float bias = cb[d * 512 + ch];

    union { u16 s[32]; uint4 v[4]; } o;
    #pragma unroll
    for (int i = 0; i < 32; ++i) {
        float acc = bias + c0 * b2f(wd.s[5 + i]) + c1 * b2f(wd.s[6 + i])
                         + c2 * b2f(wd.s[7 + i]) + c3 * b2f(wd.s[8 + i]);
        o.s[i] = f2b(silu(acc));
    }
    u16* orow = uT + ((size_t)d * 512 + ch) * 8192 + b * 2048 + l0;
    #pragma unroll
    for (int i = 0; i < 4; ++i) ((uint4*)orow)[i] = o.v[i];
}

// ---------------------------------------------------------------------------
// Single-pass chunked associative scan, 8 states/thread (R8 structure).
// ---------------------------------------------------------------------------
__global__ __launch_bounds__(256)
void scan_kernel(const u16* __restrict__ xzT, const u16* __restrict__ uT,
                 const u16* __restrict__ dbcT, const float* __restrict__ A_log,
                 const float* __restrict__ Dp, float* __restrict__ gsum)
{
    __shared__ float part[4];
    const int tid  = threadIdx.x;
    const int wv   = tid >> 6;
    const int lane = tid & 63;
    const int blk  = blockIdx.x;              // 0..2047
    const int bd   = blk >> 8;
    const int d    = bd >> 2, b = bd & 3;
    const int ch   = (blk & 255) * 2 + (wv >> 1);
    const int nh   = (wv & 1) * 8;

    const u16* pdt = xzT + ((size_t)d * 1024 + ch) * 8192 + b * 2048 + lane * 32;
    const u16* pz  = xzT + ((size_t)d * 1024 + 512 + ch) * 8192 + b * 2048 + lane * 32;
    const u16* pu  = uT + ((size_t)d * 512 + ch) * 8192 + b * 2048 + lane * 32;
    const u16* pB  = dbcT + ((size_t)d * 48 + 16 + nh) * 8192 + b * 2048 + lane * 32;
    const u16* pC  = dbcT + ((size_t)d * 48 + 32 + nh) * 8192 + b * 2048 + lane * 32;

    float a[8];
    #pragma unroll
    for (int n = 0; n < 8; ++n)
        a[n] = -__expf(A_log[(d * 512 + ch) * 16 + nh + n]);
    const float DvEff = (wv & 1) ? 0.f : Dp[d * 512 + ch];

    float P[8], S[8], beta[8];
    #pragma unroll
    for (int n = 0; n < 8; ++n) { P[n] = 1.f; S[n] = 0.f; beta[n] = 0.f; }
    float alpha = 0.f;

    #pragma unroll 1
    for (int gq = 0; gq < 4; ++gq) {
        uint4 vdt = *(const uint4*)(pdt + gq * 8);
        uint4 vu  = *(const uint4*)(pu + gq * 8);
        uint4 vz  = *(const uint4*)(pz + gq * 8);
        const u16* ds = (const u16*)&vdt;
        const u16* us = (const u16*)&vu;
        const u16* zs = (const u16*)&vz;
        float dtv[8], duv[8], gv[8];
        #pragma unroll
        for (int s = 0; s < 8; ++s) {
            float dt = b2f(ds[s]), uv = b2f(us[s]), zv = b2f(zs[s]);
            dtv[s] = dt;
            duv[s] = dt * uv;
            float g = silu(zv);
            gv[s] = g;
            alpha = fmaf(g * uv, DvEff, alpha);
        }
        #pragma unroll
        for (int n = 0; n < 8; ++n) {
            uint4 Bq = *(const uint4*)(pB + (size_t)n * 8192 + gq * 8);
            uint4 Cq = *(const uint4*)(pC + (size_t)n * 8192 + gq * 8);
            unsigned int bw[4] = {Bq.x, Bq.y, Bq.z, Bq.w};
            unsigned int cw2[4] = {Cq.x, Cq.y, Cq.z, Cq.w};
            float tp = P[n], ts = S[n], tb = beta[n], an = a[n];
            #pragma unroll
            for (int w2 = 0; w2 < 4; ++w2) {
                float B0, B1, C0, C1;
                unpk2(bw[w2], B0, B1);
                unpk2(cw2[w2], C0, C1);
                int s0 = 2 * w2, s1 = s0 + 1;
                float dA0 = __expf(dtv[s0] * an);
                ts = fmaf(dA0, ts, duv[s0] * B0);
                tp *= dA0;
                float gC0 = gv[s0] * C0;
                alpha = fmaf(gC0, ts, alpha);
                tb = fmaf(gC0, tp, tb);
                float dA1 = __expf(dtv[s1] * an);
                ts = fmaf(dA1, ts, duv[s1] * B1);
                tp *= dA1;
                float gC1 = gv[s1] * C1;
                alpha = fmaf(gC1, ts, alpha);
                tb = fmaf(gC1, tp, tb);
            }
            P[n] = tp; S[n] = ts; beta[n] = tb;
        }
    }
    #pragma unroll
    for (int off = 1; off < 64; off <<= 1) {
        #pragma unroll
        for (int n = 0; n < 8; ++n) {
            float Pp = __shfl_up(P[n], off);
            float Sp = __shfl_up(S[n], off);
            Pp = (lane >= off) ? Pp : 1.f;
            Sp = (lane >= off) ? Sp : 0.f;
            S[n] = fmaf(P[n], Sp, S[n]);
            P[n] *= Pp;
        }
    }
    float gacc = alpha;
    #pragma unroll
    for (int n = 0; n < 8; ++n) {
        float Hs = __shfl_up(S[n], 1);
        float h0 = (lane == 0) ? 0.f : Hs;
        gacc = fmaf(beta[n], h0, gacc);
    }
    #pragma unroll
    for (int off = 1; off < 64; off <<= 1) gacc += __shfl_xor(gacc, off);
    if (lane == 0) part[wv] = gacc;
    __syncthreads();
    if (tid < 2)
        gsum[bd * 512 + (blk & 255) * 2 + tid] = part[tid * 2] + part[tid * 2 + 1];
}

// ---------------------------------------------------------------------------
// Epilogue projections. One block per batch b.
// ---------------------------------------------------------------------------
__global__ __launch_bounds__(256)
void final_kernel(const float* __restrict__ gsum, const float* __restrict__ out_w,
                  const float* __restrict__ op_w, const float* __restrict__ op_b,
                  float* __restrict__ out)
{
    __shared__ float gs[1024];
    __shared__ float embd[512];
    int b = blockIdx.x, tid = threadIdx.x;
    for (int i = tid; i < 1024; i += 256) {
        int dd = i >> 9, c = i & 511;
        gs[i] = gsum[(dd * 4 + b) * 512 + c];
    }
    __syncthreads();
    for (int j = tid; j < 512; j += 256) {
        int dd = j >> 8, jj = j & 255;
        const float* wp = out_w + (size_t)(dd * 256 + jj) * 512;
        const float* gp = gs + dd * 512;
        float s = 0.f;
        for (int c = 0; c < 512; ++c) s = fmaf(gp[c], wp[c], s);
        embd[j] = s * (1.0f / 2048.0f);
    }
    __syncthreads();
    {
        int i = tid;
        float s = op_b[i];
        const float* wp = op_w + (size_t)i * 512;
        for (int j = 0; j < 512; ++j) s = fmaf(embd[j], wp[j], s);
        out[b * 256 + i] = s;
    }
}

// ---------------------------------------------------------------------------
extern "C" void kernel_launch(void* const* d_in, const int* in_sizes, int n_in,
                              void* d_out, int out_size, void* d_ws, size_t ws_size,
                              hipStream_t stream)
{
    (void)in_sizes; (void)n_in; (void)out_size; (void)ws_size;
    const float* x       = (const float*)d_in[0];   // [4,2048,512]
    const float* ip_w    = (const float*)d_in[1];   // [256,512]
    const float* ip_b    = (const float*)d_in[2];   // [256]
    const float* in_w    = (const float*)d_in[3];   // [2,1024,256]
    const float* conv_w  = (const float*)d_in[4];   // [2,512,4]
    const float* conv_b  = (const float*)d_in[5];   // [2,512]
    const float* xproj_w = (const float*)d_in[6];   // [2,48,512]
    const float* dt_w    = (const float*)d_in[7];   // [2,512,16]
    const float* dt_b    = (const float*)d_in[8];   // [2,512]
    const float* A_log   = (const float*)d_in[9];   // [2,512,16]
    const float* Dp      = (const float*)d_in[10];  // [2,512]
    const float* out_w   = (const float*)d_in[11];  // [2,256,512]
    const float* op_w    = (const float*)d_in[12];  // [256,512]
    const float* op_b    = (const float*)d_in[13];  // [256]
    float* out = (float*)d_out;                     // [4,256]

    // Workspace (53,362,688 B):
    //   xzT   [0,        33554432)  [2][1024][8192] bf16 time-major
    //   uT    [33554432, 50331648)  [2][512][8192]  bf16 time-major
    //   hbuf  alias @33554432       [8192][256]     bf16 (dead before uT write)
    //   dbcT  [50331648, 51904512)  [2][48][8192]   bf16 n-major
    //   gsum  [51904512, 51920896)  [8][512]        fp32
    //   wpack [51920896, 53362688)  720896 bf16: ip_w|in_w|xproj_w|dt_w
    char* ws = (char*)d_ws;
    u16*   xzT  = (u16*)(ws + 0);
    u16*   uT   = (u16*)(ws + 33554432);
    u16*   hbuf = (u16*)(ws + 33554432);
    u16*   dbcT = (u16*)(ws + 50331648);
    float* gsum = (float*)(ws + 51904512);
    u16*   wpk  = (u16*)(ws + 51920896);
    u16*   ipw_b   = wpk;               // 131072
    u16*   inw_b   = wpk + 131072;      // 524288
    u16*   xprojw_b= wpk + 655360;      // 49152
    u16*   dtw_b   = wpk + 704512;      // 16384

    dim3 blk(256);

    // 0) prepack weights fp32->bf16
    pack_weights<<<dim3(352), blk, 0, stream>>>(ip_w, in_w, xproj_w, dt_w, wpk);

    // 1) in_proj: hbuf = x @ ip_w^T + ip_b   [8192,256] row-major (128-tile)
    gemm128<1, 0, 0><<<dim3(2, 64, 1), blk, 0, stream>>>(
        x, ipw_b, ip_b, hbuf, 8192, 256, 512, 512, 512, 256, 0, 0, 0);

    // 2) xzT[d] = (hbuf(_flip d) @ in_w[d]^T)^T   [1024][8192] (128-tile, grid.z=dir)
    gemm128<0, 1, 1><<<dim3(8, 64, 2), blk, 0, stream>>>(
        hbuf, inw_b, nullptr, xzT, 8192, 1024, 256, 256, 256, 8192,
        0, (size_t)1024 * 256, (size_t)1024 * 8192);

    // 3) uT = silu(causal_conv(xiT) + cb)
    conv_silu_T<<<dim3(1024), blk, 0, stream>>>(xzT, conv_w, conv_b, uT);

    // 4) dbcT[d] = ((uT[d])^T @ xproj_w[d]^T)^T   [48][8192] n-major
    gemm64<0, 1, 1><<<dim3(1, 128, 2), blk, 0, stream>>>(
        uT, xprojw_b, nullptr, dbcT, 8192, 48, 512, 8192, 512, 8192,
        (size_t)512 * 8192, (size_t)48 * 512, (size_t)48 * 8192, 0);

    // 5) dtT[d] = softplus(dbcT[0:16]^T @ dt_w[d]^T + dt_b[d])^T -> xzT rows 0:512
    gemm64<1, 1, 1><<<dim3(8, 128, 2), blk, 0, stream>>>(
        dbcT, dtw_b, dt_b, xzT, 8192, 512, 16, 8192, 16, 8192,
        (size_t)48 * 8192, (size_t)512 * 16, (size_t)1024 * 8192, 512);

    // 6) single-pass chunked scan + gated mean-pool
    scan_kernel<<<dim3(2048), blk, 0, stream>>>(xzT, uT, dbcT, A_log, Dp, gsum);

    // 7) projections to output
    final_kernel<<<dim3(4), blk, 0, stream>>>(gsum, out_w, op_w, op_b, out);
}

// Round 10
// 264.245 us; speedup vs baseline: 3.4585x; 1.1070x over previous
//
#include <hip/hip_runtime.h>
#include <stdint.h>

// MambaEncoder on MI355X (gfx950).
// ALL inputs and the output are FLOAT32. Intermediates bf16 in workspace,
// TIME-MAJOR; dbc n-major. Weights prepacked fp32->bf16. CTRANS GEMM
// epilogues go through an LDS transpose so global stores are dense uint4
// rows (R9: direct CT stores touched 16 lines/instr). Final projections are
// two wave-cooperative GEMV kernels (R9: 4-block final_kernel was
// latency-bound on 64-line strided loads).
// Scan: single-pass chunked associative scan, 8 states/thread, exp via
// v_exp_f32 with log2e folded into the A coefficients.

typedef unsigned short u16;
typedef __bf16 bf16x8 __attribute__((ext_vector_type(8)));
typedef float f32x4 __attribute__((ext_vector_type(4)));

#define LOG2E 1.44269504088896f

__device__ __forceinline__ float b2f(u16 h) {
    union { unsigned int u; float f; } c; c.u = ((unsigned int)h) << 16; return c.f;
}
__device__ __forceinline__ u16 f2b(float f) {   // round-to-nearest-even
    union { float f; unsigned int u; } c; c.f = f;
    unsigned int r = c.u + 0x7FFFu + ((c.u >> 16) & 1u);
    return (u16)(r >> 16);
}
__device__ __forceinline__ void unpk2(unsigned int u, float& lo, float& hi) {
    union { unsigned int x; float f; } c0, c1;
    c0.x = u << 16; c1.x = u & 0xffff0000u;
    lo = c0.f; hi = c1.f;
}
__device__ __forceinline__ float silu(float x) {
    return x * __builtin_amdgcn_rcpf(1.f + __builtin_amdgcn_exp2f(-LOG2E * x));
}

// ---------------------------------------------------------------------------
// Weight prepack: fp32 -> bf16 (RNE). Segments:
//   ip_w 131072 | in_w 524288 | xproj_w 49152 | dt_w 16384
// ---------------------------------------------------------------------------
__global__ __launch_bounds__(256)
void pack_weights(const float* __restrict__ s0, const float* __restrict__ s1,
                  const float* __restrict__ s2, const float* __restrict__ s3,
                  u16* __restrict__ dst)
{
    int idx = (blockIdx.x * 256 + threadIdx.x) * 8;
    const float* src; int off;
    if (idx < 131072)      { src = s0; off = idx; }
    else if (idx < 655360) { src = s1; off = idx - 131072; }
    else if (idx < 704512) { src = s2; off = idx - 655360; }
    else                   { src = s3; off = idx - 704512; }
    float4 f0 = *(const float4*)(src + off);
    float4 f1 = *(const float4*)(src + off + 4);
    union { u16 s[8]; uint4 v; } t;
    t.s[0] = f2b(f0.x); t.s[1] = f2b(f0.y); t.s[2] = f2b(f0.z); t.s[3] = f2b(f0.w);
    t.s[4] = f2b(f1.x); t.s[5] = f2b(f1.y); t.s[6] = f2b(f1.z); t.s[7] = f2b(f1.w);
    *(uint4*)(dst + idx) = t.v;
}

// ---------------------------------------------------------------------------
// 128x128 MFMA GEMM: C = A @ W^T + bias. M%128==0, N%128==0, K%32==0.
// W bf16 prepacked. AF32: A fp32. CTRANS: CT[n][m] via LDS transpose,
// dense uint4 stores. ZFLIP: dir-1 time flip on A rows.
// ---------------------------------------------------------------------------
template<int AF32, int CTRANS, int ZFLIP>
__global__ __launch_bounds__(256)
void gemm128(const void* __restrict__ Av, const u16* __restrict__ Wb,
             const float* __restrict__ bias, u16* __restrict__ C,
             int M, int N, int K, int lda, int ldw, int ldc,
             size_t azs, size_t wzs, size_t czs)
{
    __shared__ u16 sh[10240];       // As 128x40 | Ws 128x40 ; reused by epilogue
    u16* As = sh;
    u16* Ws = sh + 5120;
    const int z    = blockIdx.z;
    const int flip = ZFLIP ? z : 0;
    Wb += (size_t)z * wzs;
    C  += (size_t)z * czs;
    const u16*   A16 = (const u16*)Av + (AF32 ? 0 : (size_t)z * azs);
    const float* A32 = (const float*)Av + (AF32 ? (size_t)z * azs : 0);

    const int tid  = threadIdx.x;
    const int n0   = blockIdx.x * 128;
    const int m0   = blockIdx.y * 128;
    const int w    = tid >> 6;
    const int lane = tid & 63;
    const int r16  = lane & 15;
    const int q    = lane >> 4;
    const int wm   = (w >> 1) * 64;
    const int wn   = (w & 1) * 64;

    f32x4 acc[4][4];
    #pragma unroll
    for (int i = 0; i < 4; ++i)
        #pragma unroll
        for (int j = 0; j < 4; ++j) acc[i][j] = (f32x4){0.f, 0.f, 0.f, 0.f};

    const int KT = K >> 5;
    for (int kt = 0; kt < KT; ++kt) {
        #pragma unroll
        for (int rr = 0; rr < 2; ++rr) {
            int idx = rr * 256 + tid;
            int row = idx >> 2;
            int col = (kt << 5) + (idx & 3) * 8;
            {   // A
                int m   = m0 + row;
                int src = flip ? ((m & ~2047) | (2047 - (m & 2047))) : m;
                union { u16 s[8]; uint4 v; } t;
                if (AF32) {
                    const float* sp = A32 + (size_t)src * lda + col;
                    float4 f0 = *(const float4*)sp;
                    float4 f1 = *(const float4*)(sp + 4);
                    t.s[0] = f2b(f0.x); t.s[1] = f2b(f0.y);
                    t.s[2] = f2b(f0.z); t.s[3] = f2b(f0.w);
                    t.s[4] = f2b(f1.x); t.s[5] = f2b(f1.y);
                    t.s[6] = f2b(f1.z); t.s[7] = f2b(f1.w);
                } else {
                    t.v = *(const uint4*)(A16 + (size_t)src * lda + col);
                }
                *(uint4*)(&As[row * 40 + (idx & 3) * 8]) = t.v;
            }
            {   // W
                uint4 v = *(const uint4*)(Wb + (size_t)(n0 + row) * ldw + col);
                *(uint4*)(&Ws[row * 40 + (idx & 3) * 8]) = v;
            }
        }
        __syncthreads();
        bf16x8 af[4], wf[4];
        #pragma unroll
        for (int i = 0; i < 4; ++i)
            af[i] = *(const bf16x8*)(&As[(wm + i * 16 + r16) * 40 + q * 8]);
        #pragma unroll
        for (int j = 0; j < 4; ++j)
            wf[j] = *(const bf16x8*)(&Ws[(wn + j * 16 + r16) * 40 + q * 8]);
        #pragma unroll
        for (int i = 0; i < 4; ++i)
            #pragma unroll
            for (int j = 0; j < 4; ++j)
                acc[i][j] = __builtin_amdgcn_mfma_f32_16x16x32_bf16(af[i], wf[j], acc[i][j], 0, 0, 0);
        __syncthreads();
    }
    if (CTRANS) {
        // two n-halves of 64 rows through LDS (stride 132 u16 -> dense stores)
        #pragma unroll
        for (int h = 0; h < 2; ++h) {
            if ((w & 1) == h) {
                #pragma unroll
                for (int j = 0; j < 4; ++j) {
                    float bv = bias ? bias[n0 + wn + j * 16 + r16] : 0.f;
                    #pragma unroll
                    for (int i = 0; i < 4; ++i) {
                        union { u16 s[4]; uint2 v; } pk;
                        #pragma unroll
                        for (int rg = 0; rg < 4; ++rg) pk.s[rg] = f2b(acc[i][j][rg] + bv);
                        *(uint2*)(&sh[(j * 16 + r16) * 132 + wm + i * 16 + q * 4]) = pk.v;
                    }
                }
            }
            __syncthreads();
            int row  = tid >> 2, part = tid & 3;
            const u16* sp2 = &sh[row * 132 + part * 32];
            u16* dp = C + (size_t)(n0 + h * 64 + row) * ldc + m0 + part * 32;
            uint4 v0 = *(const uint4*)(sp2);
            uint4 v1 = *(const uint4*)(sp2 + 8);
            uint4 v2 = *(const uint4*)(sp2 + 16);
            uint4 v3 = *(const uint4*)(sp2 + 24);
            ((uint4*)dp)[0] = v0; ((uint4*)dp)[1] = v1;
            ((uint4*)dp)[2] = v2; ((uint4*)dp)[3] = v3;
            __syncthreads();
        }
    } else {
        #pragma unroll
        for (int j = 0; j < 4; ++j) {
            int n = n0 + wn + j * 16 + r16;
            float bv = bias ? bias[n] : 0.f;
            #pragma unroll
            for (int i = 0; i < 4; ++i)
                #pragma unroll
                for (int rg = 0; rg < 4; ++rg) {
                    int m = m0 + wm + i * 16 + q * 4 + rg;
                    C[(size_t)m * ldc + n] = f2b(acc[i][j][rg] + bv);
                }
        }
    }
}

// ---------------------------------------------------------------------------
// 64x64 MFMA GEMM (skinny N/K). W bf16 prepacked. A bf16.
// ATRANS: A stored [K][M], rows >= K read as 0. CTRANS via LDS transpose.
// ACT: 0 none, 1 softplus.
// ---------------------------------------------------------------------------
template<int ACT, int ATRANS, int CTRANS>
__global__ __launch_bounds__(256)
void gemm64(const u16* __restrict__ A16, const u16* __restrict__ Wb,
            const float* __restrict__ bias, u16* __restrict__ C,
            int M, int N, int K, int lda, int ldw, int ldc,
            size_t azs, size_t wzs, size_t czs, int bzs)
{
    __shared__ u16 sh[5120];        // As 64x40 | Ws 64x40 ; reused by epilogue
    u16* As = sh;
    u16* Ws = sh + 2560;
    const int z = blockIdx.z;
    Wb += (size_t)z * wzs;
    C  += (size_t)z * czs;
    if (bias) bias += (size_t)z * bzs;
    const u16* A = A16 + (size_t)z * azs;

    const int tid  = threadIdx.x;
    const int n0   = blockIdx.x * 64;
    const int m0   = blockIdx.y * 64;
    const int r    = tid >> 2;
    const int seg  = tid & 3;
    const int w    = tid >> 6;
    const int lane = tid & 63;
    const int r16  = lane & 15;
    const int q    = lane >> 4;

    f32x4 acc[4];
    #pragma unroll
    for (int i = 0; i < 4; ++i) acc[i] = (f32x4){0.f, 0.f, 0.f, 0.f};

    const int KT = (K + 31) >> 5;
    for (int kt = 0; kt < KT; ++kt) {
        const int kk = (kt << 5) + seg * 8;
        if (ATRANS) {
            int k  = tid >> 3;
            int sg = tid & 7;
            int kd = (kt << 5) + k;
            uint4 v = (uint4){0, 0, 0, 0};
            if (kd < K) v = *(const uint4*)(A + (size_t)kd * lda + m0 + sg * 8);
            const u16* vs = (const u16*)&v;
            #pragma unroll
            for (int e = 0; e < 8; ++e) As[(sg * 8 + e) * 40 + k] = vs[e];
        } else {
            const u16* sp = A + (size_t)(m0 + r) * lda;
            union { u16 s[8]; uint4 v; } t;
            if (kk + 8 <= K) {
                t.v = *(const uint4*)(sp + kk);
            } else {
                #pragma unroll
                for (int e = 0; e < 8; ++e)
                    t.s[e] = ((kk + e) < K) ? sp[kk + e] : (u16)0;
            }
            *(uint4*)(&As[r * 40 + seg * 8]) = t.v;
        }
        {   // W row n (bf16)
            int n = n0 + r;
            const u16* sp = Wb + (size_t)n * ldw;
            union { u16 s[8]; uint4 v; } t;
            if (n < N && kk + 8 <= K) {
                t.v = *(const uint4*)(sp + kk);
            } else {
                #pragma unroll
                for (int e = 0; e < 8; ++e)
                    t.s[e] = (n < N && (kk + e) < K) ? sp[kk + e] : (u16)0;
            }
            *(uint4*)(&Ws[r * 40 + seg * 8]) = t.v;
        }
        __syncthreads();
        bf16x8 af = *(const bf16x8*)(&As[(w * 16 + r16) * 40 + q * 8]);
        #pragma unroll
        for (int nt = 0; nt < 4; ++nt) {
            bf16x8 wf = *(const bf16x8*)(&Ws[(nt * 16 + r16) * 40 + q * 8]);
            acc[nt] = __builtin_amdgcn_mfma_f32_16x16x32_bf16(af, wf, acc[nt], 0, 0, 0);
        }
        __syncthreads();
    }
    if (CTRANS) {
        // 64x64 tile through LDS (stride 68 u16), dense uint4 row stores
        #pragma unroll
        for (int nt = 0; nt < 4; ++nt) {
            float bv = bias ? bias[n0 + nt * 16 + r16] : 0.f;
            union { u16 s[4]; uint2 v; } pk;
            #pragma unroll
            for (int rg = 0; rg < 4; ++rg) {
                float v = acc[nt][rg] + bv;
                if (ACT == 1) v = (v > 20.f) ? v : __logf(1.f + __expf(v));
                pk.s[rg] = f2b(v);
            }
            *(uint2*)(&sh[(nt * 16 + r16) * 68 + w * 16 + q * 4]) = pk.v;
        }
        __syncthreads();
        int row  = tid >> 2, part = tid & 3;
        if (n0 + row < N) {
            const u16* sp2 = &sh[row * 68 + part * 16];
            u16* dp = C + (size_t)(n0 + row) * ldc + m0 + part * 16;
            uint4 v0 = *(const uint4*)(sp2);
            uint4 v1 = *(const uint4*)(sp2 + 8);
            ((uint4*)dp)[0] = v0; ((uint4*)dp)[1] = v1;
        }
    } else {
        #pragma unroll
        for (int nt = 0; nt < 4; ++nt) {
            int n = n0 + nt * 16 + r16;
            if (n >= N) continue;
            float bv = bias ? bias[n] : 0.f;
            #pragma unroll
            for (int rg = 0; rg < 4; ++rg) {
                int m = m0 + w * 16 + q * 4 + rg;
                float v = acc[nt][rg] + bv;
                if (ACT == 1) v = (v > 20.f) ? v : __logf(1.f + __expf(v));
                C[(size_t)m * ldc + n] = f2b(v);
            }
        }
    }
}

// ---------------------------------------------------------------------------
// Depthwise causal conv (4 taps) + silu, time-major.
// ---------------------------------------------------------------------------
__global__ __launch_bounds__(256)
void conv_silu_T(const u16* __restrict__ xzT, const float* __restrict__ cw,
                 const float* __restrict__ cb, u16* __restrict__ uT)
{
    int g    = blockIdx.x * 256 + threadIdx.x;
    int tile = g & 63;
    int b    = (g >> 6) & 3;
    int ch   = (g >> 8) & 511;
    int d    = g >> 17;
    int l0   = tile * 32;
    const u16* row = xzT + ((size_t)d * 1024 + ch) * 8192 + b * 2048;

    union { u16 s[40]; uint4 v[5]; } wd;
    wd.v[0] = (tile > 0) ? *(const uint4*)(row + l0 - 8) : (uint4){0, 0, 0, 0};
    #pragma unroll
    for (int i = 0; i < 4; ++i) wd.v[1 + i] = *(const uint4*)(row + l0 + i * 8);

    const float* wp = cw + (size_t)(d * 512 + ch) * 4;
    float c0 = wp[0], c1 = wp[1], c2 = wp[2], c3 = wp[3];
    float bias = cb[d * 512 + ch];

    union { u16 s[32]; uint4 v[4]; } o;
    #pragma unroll
    for (int i = 0; i < 32; ++i) {
        float acc = bias + c0 * b2f(wd.s[5 + i]) + c1 * b2f(wd.s[6 + i])
                         + c2 * b2f(wd.s[7 + i]) + c3 * b2f(wd.s[8 + i]);
        o.s[i] = f2b(silu(acc));
    }
    u16* orow = uT + ((size_t)d * 512 + ch) * 8192 + b * 2048 + l0;
    #pragma unroll
    for (int i = 0; i < 4; ++i) ((uint4*)orow)[i] = o.v[i];
}

// ---------------------------------------------------------------------------
// Single-pass chunked associative scan, 8 states/thread (R8 structure).
// exp via v_exp_f32 (log2e folded into a[]).
// ---------------------------------------------------------------------------
__global__ __launch_bounds__(256)
void scan_kernel(const u16* __restrict__ xzT, const u16* __restrict__ uT,
                 const u16* __restrict__ dbcT, const float* __restrict__ A_log,
                 const float* __restrict__ Dp, float* __restrict__ gsum)
{
    __shared__ float part[4];
    const int tid  = threadIdx.x;
    const int wv   = tid >> 6;
    const int lane = tid & 63;
    const int blk  = blockIdx.x;              // 0..2047
    const int bd   = blk >> 8;
    const int d    = bd >> 2, b = bd & 3;
    const int ch   = (blk & 255) * 2 + (wv >> 1);
    const int nh   = (wv & 1) * 8;

    const u16* pdt = xzT + ((size_t)d * 1024 + ch) * 8192 + b * 2048 + lane * 32;
    const u16* pz  = xzT + ((size_t)d * 1024 + 512 + ch) * 8192 + b * 2048 + lane * 32;
    const u16* pu  = uT + ((size_t)d * 512 + ch) * 8192 + b * 2048 + lane * 32;
    const u16* pB  = dbcT + ((size_t)d * 48 + 16 + nh) * 8192 + b * 2048 + lane * 32;
    const u16* pC  = dbcT + ((size_t)d * 48 + 32 + nh) * 8192 + b * 2048 + lane * 32;

    float a[8];
    #pragma unroll
    for (int n = 0; n < 8; ++n)
        a[n] = -LOG2E * __expf(A_log[(d * 512 + ch) * 16 + nh + n]);
    const float DvEff = (wv & 1) ? 0.f : Dp[d * 512 + ch];

    float P[8], S[8], beta[8];
    #pragma unroll
    for (int n = 0; n < 8; ++n) { P[n] = 1.f; S[n] = 0.f; beta[n] = 0.f; }
    float alpha = 0.f;

    #pragma unroll 1
    for (int gq = 0; gq < 4; ++gq) {
        uint4 vdt = *(const uint4*)(pdt + gq * 8);
        uint4 vu  = *(const uint4*)(pu + gq * 8);
        uint4 vz  = *(const uint4*)(pz + gq * 8);
        const u16* ds = (const u16*)&vdt;
        const u16* us = (const u16*)&vu;
        const u16* zs = (const u16*)&vz;
        float dtv[8], duv[8], gv[8];
        #pragma unroll
        for (int s = 0; s < 8; ++s) {
            float dt = b2f(ds[s]), uv = b2f(us[s]), zv = b2f(zs[s]);
            dtv[s] = dt;
            duv[s] = dt * uv;
            float g = silu(zv);
            gv[s] = g;
            alpha = fmaf(g * uv, DvEff, alpha);
        }
        #pragma unroll
        for (int n = 0; n < 8; ++n) {
            uint4 Bq = *(const uint4*)(pB + (size_t)n * 8192 + gq * 8);
            uint4 Cq = *(const uint4*)(pC + (size_t)n * 8192 + gq * 8);
            unsigned int bw[4] = {Bq.x, Bq.y, Bq.z, Bq.w};
            unsigned int cw2[4] = {Cq.x, Cq.y, Cq.z, Cq.w};
            float tp = P[n], ts = S[n], tb = beta[n], an = a[n];
            #pragma unroll
            for (int w2 = 0; w2 < 4; ++w2) {
                float B0, B1, C0, C1;
                unpk2(bw[w2], B0, B1);
                unpk2(cw2[w2], C0, C1);
                int s0 = 2 * w2, s1 = s0 + 1;
                float dA0 = __builtin_amdgcn_exp2f(dtv[s0] * an);
                ts = fmaf(dA0, ts, duv[s0] * B0);
                tp *= dA0;
                float gC0 = gv[s0] * C0;
                alpha = fmaf(gC0, ts, alpha);
                tb = fmaf(gC0, tp, tb);
                float dA1 = __builtin_amdgcn_exp2f(dtv[s1] * an);
                ts = fmaf(dA1, ts, duv[s1] * B1);
                tp *= dA1;
                float gC1 = gv[s1] * C1;
                alpha = fmaf(gC1, ts, alpha);
                tb = fmaf(gC1, tp, tb);
            }
            P[n] = tp; S[n] = ts; beta[n] = tb;
        }
    }
    #pragma unroll
    for (int off = 1; off < 64; off <<= 1) {
        #pragma unroll
        for (int n = 0; n < 8; ++n) {
            float Pp = __shfl_up(P[n], off);
            float Sp = __shfl_up(S[n], off);
            Pp = (lane >= off) ? Pp : 1.f;
            Sp = (lane >= off) ? Sp : 0.f;
            S[n] = fmaf(P[n], Sp, S[n]);
            P[n] *= Pp;
        }
    }
    float gacc = alpha;
    #pragma unroll
    for (int n = 0; n < 8; ++n) {
        float Hs = __shfl_up(S[n], 1);
        float h0 = (lane == 0) ? 0.f : Hs;
        gacc = fmaf(beta[n], h0, gacc);
    }
    #pragma unroll
    for (int off = 1; off < 64; off <<= 1) gacc += __shfl_xor(gacc, off);
    if (lane == 0) part[wv] = gacc;
    __syncthreads();
    if (tid < 2)
        gsum[bd * 512 + (blk & 255) * 2 + tid] = part[tid * 2] + part[tid * 2 + 1];
}

// ---------------------------------------------------------------------------
// Final projection, phase A: embd[b][j] = (1/L) * dot(gbar-concat, out_w row).
// Grid 32 blocks (b x 8 j-groups); one wave per j, lanes span the 512-dot.
// ---------------------------------------------------------------------------
__global__ __launch_bounds__(256)
void final_embd(const float* __restrict__ gsum, const float* __restrict__ out_w,
                float* __restrict__ embd)
{
    const int b  = blockIdx.x >> 3;
    const int jg = blockIdx.x & 7;
    const int wv = threadIdx.x >> 6;
    const int lane = threadIdx.x & 63;
    for (int t = 0; t < 16; ++t) {
        int j  = jg * 64 + wv * 16 + t;
        int dd = j >> 8, jj = j & 255;
        const float* wp = out_w + (size_t)(dd * 256 + jj) * 512 + lane * 8;
        const float* gp = gsum + (size_t)(dd * 4 + b) * 512 + lane * 8;
        float4 w0 = *(const float4*)wp;
        float4 w1 = *(const float4*)(wp + 4);
        float4 g0 = *(const float4*)gp;
        float4 g1 = *(const float4*)(gp + 4);
        float s = w0.x * g0.x + w0.y * g0.y + w0.z * g0.z + w0.w * g0.w
                + w1.x * g1.x + w1.y * g1.y + w1.z * g1.z + w1.w * g1.w;
        #pragma unroll
        for (int off = 1; off < 64; off <<= 1) s += __shfl_xor(s, off);
        if (lane == 0) embd[b * 512 + j] = s * (1.0f / 2048.0f);
    }
}

// ---------------------------------------------------------------------------
// Final projection, phase B: out[b][i] = dot(embd[b], op_w row) + op_b[i].
// Grid 16 blocks (b x 4 i-groups); one wave per i.
// ---------------------------------------------------------------------------
__global__ __launch_bounds__(256)
void final_out(const float* __restrict__ embd, const float* __restrict__ op_w,
               const float* __restrict__ op_b, float* __restrict__ out)
{
    const int b  = blockIdx.x >> 2;
    const int ig = blockIdx.x & 3;
    const int wv = threadIdx.x >> 6;
    const int lane = threadIdx.x & 63;
    for (int t = 0; t < 16; ++t) {
        int i = ig * 64 + wv * 16 + t;
        const float* wp = op_w + (size_t)i * 512 + lane * 8;
        const float* ep = embd + (size_t)b * 512 + lane * 8;
        float4 w0 = *(const float4*)wp;
        float4 w1 = *(const float4*)(wp + 4);
        float4 e0 = *(const float4*)ep;
        float4 e1 = *(const float4*)(ep + 4);
        float s = w0.x * e0.x + w0.y * e0.y + w0.z * e0.z + w0.w * e0.w
                + w1.x * e1.x + w1.y * e1.y + w1.z * e1.z + w1.w * e1.w;
        #pragma unroll
        for (int off = 1; off < 64; off <<= 1) s += __shfl_xor(s, off);
        if (lane == 0) out[b * 256 + i] = s + op_b[i];
    }
}

// ---------------------------------------------------------------------------
extern "C" void kernel_launch(void* const* d_in, const int* in_sizes, int n_in,
                              void* d_out, int out_size, void* d_ws, size_t ws_size,
                              hipStream_t stream)
{
    (void)in_sizes; (void)n_in; (void)out_size; (void)ws_size;
    const float* x       = (const float*)d_in[0];   // [4,2048,512]
    const float* ip_w    = (const float*)d_in[1];   // [256,512]
    const float* ip_b    = (const float*)d_in[2];   // [256]
    const float* in_w    = (const float*)d_in[3];   // [2,1024,256]
    const float* conv_w  = (const float*)d_in[4];   // [2,512,4]
    const float* conv_b  = (const float*)d_in[5];   // [2,512]
    const float* xproj_w = (const float*)d_in[6];   // [2,48,512]
    const float* dt_w    = (const float*)d_in[7];   // [2,512,16]
    const float* dt_b    = (const float*)d_in[8];   // [2,512]
    const float* A_log   = (const float*)d_in[9];   // [2,512,16]
    const float* Dp      = (const float*)d_in[10];  // [2,512]
    const float* out_w   = (const float*)d_in[11];  // [2,256,512]
    const float* op_w    = (const float*)d_in[12];  // [256,512]
    const float* op_b    = (const float*)d_in[13];  // [256]
    float* out = (float*)d_out;                     // [4,256]

    // Workspace (53,370,880 B):
    //   xzT   [0,        33554432)  [2][1024][8192] bf16 time-major
    //   uT    [33554432, 50331648)  [2][512][8192]  bf16 time-major
    //   hbuf  alias @33554432       [8192][256]     bf16 (dead before uT write)
    //   dbcT  [50331648, 51904512)  [2][48][8192]   bf16 n-major
    //   gsum  [51904512, 51920896)  [8][512]        fp32
    //   wpack [51920896, 53362688)  720896 bf16: ip_w|in_w|xproj_w|dt_w
    //   embd  [53362688, 53370880)  [4][512]        fp32
    char* ws = (char*)d_ws;
    u16*   xzT  = (u16*)(ws + 0);
    u16*   uT   = (u16*)(ws + 33554432);
    u16*   hbuf = (u16*)(ws + 33554432);
    u16*   dbcT = (u16*)(ws + 50331648);
    float* gsum = (float*)(ws + 51904512);
    u16*   wpk  = (u16*)(ws + 51920896);
    float* embd = (float*)(ws + 53362688);
    u16*   ipw_b    = wpk;               // 131072
    u16*   inw_b    = wpk + 131072;      // 524288
    u16*   xprojw_b = wpk + 655360;      // 49152
    u16*   dtw_b    = wpk + 704512;      // 16384

    dim3 blk(256);

    // 0) prepack weights fp32->bf16
    pack_weights<<<dim3(352), blk, 0, stream>>>(ip_w, in_w, xproj_w, dt_w, wpk);

    // 1) in_proj: hbuf = x @ ip_w^T + ip_b   [8192,256] row-major
    gemm128<1, 0, 0><<<dim3(2, 64, 1), blk, 0, stream>>>(
        x, ipw_b, ip_b, hbuf, 8192, 256, 512, 512, 512, 256, 0, 0, 0);

    // 2) xzT[d] = (hbuf(_flip d) @ in_w[d]^T)^T   [1024][8192], grid.z = dir
    gemm128<0, 1, 1><<<dim3(8, 64, 2), blk, 0, stream>>>(
        hbuf, inw_b, nullptr, xzT, 8192, 1024, 256, 256, 256, 8192,
        0, (size_t)1024 * 256, (size_t)1024 * 8192);

    // 3) uT = silu(causal_conv(xiT) + cb)
    conv_silu_T<<<dim3(1024), blk, 0, stream>>>(xzT, conv_w, conv_b, uT);

    // 4) dbcT[d] = ((uT[d])^T @ xproj_w[d]^T)^T   [48][8192] n-major
    gemm64<0, 1, 1><<<dim3(1, 128, 2), blk, 0, stream>>>(
        uT, xprojw_b, nullptr, dbcT, 8192, 48, 512, 8192, 512, 8192,
        (size_t)512 * 8192, (size_t)48 * 512, (size_t)48 * 8192, 0);

    // 5) dtT[d] = softplus(dbcT[0:16]^T @ dt_w[d]^T + dt_b[d])^T -> xzT rows 0:512
    gemm64<1, 1, 1><<<dim3(8, 128, 2), blk, 0, stream>>>(
        dbcT, dtw_b, dt_b, xzT, 8192, 512, 16, 8192, 16, 8192,
        (size_t)48 * 8192, (size_t)512 * 16, (size_t)1024 * 8192, 512);

    // 6) single-pass chunked scan + gated mean-pool
    scan_kernel<<<dim3(2048), blk, 0, stream>>>(xzT, uT, dbcT, A_log, Dp, gsum);

    // 7) final projections (two wave-cooperative GEMVs)
    final_embd<<<dim3(32), blk, 0, stream>>>(gsum, out_w, embd);
    final_out<<<dim3(16), blk, 0, stream>>>(embd, op_w, op_b, out);
}